// Round 14
// baseline (287.780 us; speedup 1.0000x reference)
//
#include <hip/hip_runtime.h>
#include <hip/hip_bf16.h>
#include <math.h>

typedef __hip_bfloat16 bf16;
typedef __attribute__((ext_vector_type(8))) short bf16x8v;
typedef __attribute__((ext_vector_type(4))) float f32x4v;

#define NPIX 4096

__device__ __forceinline__ float b2f(bf16 v) { return __bfloat162float(v); }
__device__ __forceinline__ unsigned short f2bu(float f) {
    bf16 h = __float2bfloat16(f);
    return *(unsigned short*)&h;
}
__device__ __forceinline__ int detect_bf16(const unsigned short* __restrict__ qraw) {
    int lane = threadIdx.x & 63;
    unsigned short u = qraw[lane * 2];
    int e = (u >> 7) & 0xFF;
    unsigned long long ball = __ballot(e >= 100 && e <= 135);
    return __popcll(ball) > 32;
}
__device__ __forceinline__ float rdval(const void* s, int idx, int isbf) {
    return isbf ? b2f(((const bf16*)s)[idx]) : ((const float*)s)[idx];
}

// cw element offsets
#define OF_WO6 175680
#define OF_BO6 203328
#define OF_BO1 27904
#define OF_BO2 64832
#define OF_BO3 101760
#define OF_BO4 138688
#define OF_BO5 175616
#define OF_BQ  245232
#define OF_BK  286992
#define OF_BV  328752
#define OF_BP  370512
#define OF_BM1 412128
#define OF_BM2 453888
#define OF_FL0 454032

// ---------------- fused: convert(14) + stage_pm(10) + stage_x1(4) + prepack(11) ----------------
struct CArgs { const void* src[14]; int dstoff[14]; int n[14]; };
struct PPJob { const void* src; int dstS; int Mp, Kp, kr, mr, sstride, kind; };
struct PPArgs { PPJob j[11]; };

__global__ void misc_kernel(CArgs a, PPArgs pa, const void* __restrict__ q,
                            const void* __restrict__ k, const void* __restrict__ v,
                            const void* __restrict__ vp0, const void* __restrict__ vp1,
                            const void* __restrict__ fl0, const void* __restrict__ fl1,
                            float* __restrict__ cw, short* __restrict__ XS,
                            short* __restrict__ X1, short* __restrict__ wsS)
{
    const int isbf = detect_bf16((const unsigned short*)q);
    const int y = blockIdx.y;
    if (y < 14) {
        const int n = a.n[y];
        float* d = cw + a.dstoff[y];
        if (isbf) {
            const bf16* s = (const bf16*)a.src[y];
            for (int i = blockIdx.x * 256 + threadIdx.x; i < n; i += 256 * 16) d[i] = b2f(s[i]);
        } else {
            const float* s = (const float*)a.src[y];
            for (int i = blockIdx.x * 256 + threadIdx.x; i < n; i += 256 * 16) d[i] = s[i];
        }
    } else if (y < 24) {
        const int job = y - 14;
        const int z = job >> 1, half = job & 1;
        const int p = blockIdx.x * 256 + threadIdx.x;
        const void* srcs[5] = { q, k, k, v, v };
        const int clips[5] = { 0, 0, 1, 0, 1 };
        const size_t co = (size_t)clips[z] * 144 * NPIX;
        short* row = XS + (size_t)z * 655360 + (size_t)p * 160;
        for (int c0 = half * 72; c0 < half * 72 + 72; c0 += 8) {
            unsigned short h[8];
            if (isbf) {
                const bf16* s = (const bf16*)srcs[z] + co;
#pragma unroll
                for (int i = 0; i < 8; ++i) h[i] = f2bu(b2f(s[(size_t)(c0 + i) * NPIX + p]));
            } else {
                const float* s = (const float*)srcs[z] + co;
#pragma unroll
                for (int i = 0; i < 8; ++i) h[i] = f2bu(s[(size_t)(c0 + i) * NPIX + p]);
            }
            uint4 u;
            u.x = (unsigned)h[0] | ((unsigned)h[1] << 16);
            u.y = (unsigned)h[2] | ((unsigned)h[3] << 16);
            u.z = (unsigned)h[4] | ((unsigned)h[5] << 16);
            u.w = (unsigned)h[6] | ((unsigned)h[7] << 16);
            *(uint4*)(row + c0) = u;
        }
        if (half == 1) {
            uint4 zz; zz.x = zz.y = zz.z = zz.w = 0u;
            *(uint4*)(row + 144) = zz;
            *(uint4*)(row + 152) = zz;
        }
    } else if (y < 28) {
        const int sec = y - 24;
        const int p = blockIdx.x * 256 + threadIdx.x;
        short* row = X1 + (size_t)p * 448;
        if (sec < 3) {
            const void* srcs[3] = { q, vp0, vp1 };
            const int cbase = sec * 144;
            for (int c0 = 0; c0 < 144; c0 += 8) {
                unsigned short h[8];
                if (isbf) {
                    const bf16* s = (const bf16*)srcs[sec];
#pragma unroll
                    for (int i = 0; i < 8; ++i) h[i] = f2bu(b2f(s[(size_t)(c0 + i) * NPIX + p]));
                } else {
                    const float* s = (const float*)srcs[sec];
#pragma unroll
                    for (int i = 0; i < 8; ++i) h[i] = f2bu(s[(size_t)(c0 + i) * NPIX + p]);
                }
                uint4 u;
                u.x = (unsigned)h[0] | ((unsigned)h[1] << 16);
                u.y = (unsigned)h[2] | ((unsigned)h[3] << 16);
                u.z = (unsigned)h[4] | ((unsigned)h[5] << 16);
                u.w = (unsigned)h[6] | ((unsigned)h[7] << 16);
                *(uint4*)(row + cbase + c0) = u;
            }
        } else {
            unsigned short h[4];
            if (isbf) {
                const bf16* f0 = (const bf16*)fl0;
                const bf16* f1 = (const bf16*)fl1;
                h[0] = f2bu(b2f(f0[p]));
                h[1] = f2bu(b2f(f0[NPIX + p]));
                h[2] = f2bu(b2f(f1[p]));
                h[3] = f2bu(b2f(f1[NPIX + p]));
            } else {
                const float* f0 = (const float*)fl0;
                const float* f1 = (const float*)fl1;
                h[0] = f2bu(f0[p]);
                h[1] = f2bu(f0[NPIX + p]);
                h[2] = f2bu(f1[p]);
                h[3] = f2bu(f1[NPIX + p]);
            }
            uint4 u;
            u.x = (unsigned)h[0] | ((unsigned)h[1] << 16);
            u.y = (unsigned)h[2] | ((unsigned)h[3] << 16);
            u.z = 0u; u.w = 0u;
            *(uint4*)(row + 432) = u;
            uint4 zz; zz.x = zz.y = zz.z = zz.w = 0u;
            *(uint4*)(row + 440) = zz;
        }
    } else {
        PPJob J = pa.j[y - 28];
        const int tot = J.Mp * J.Kp;
        for (int e = blockIdx.x * 256 + threadIdx.x; e < tot; e += 256 * 16) {
            int m = e / J.Kp, kk = e - m * J.Kp;
            float vv = 0.f;
            if (J.kind == 0) { if (kk < J.kr) vv = rdval(J.src, m * J.sstride + kk, isbf); }
            else if (J.kind == 1) { if (kk < J.kr && m < J.mr) vv = rdval(J.src, kk * J.sstride + m, isbf); }
            else { int c = kk & 63, tap = kk >> 6; if (kk < J.kr) vv = rdval(J.src, m * J.sstride + c * 9 + tap, isbf); }
            wsS[J.dstS + e] = (short)f2bu(vv);
        }
    }
}

// ---------------- MFMA GEMM (KP compile-time -> fully unrolled K-loop) ----------------
struct GemmDesc {
    const short* A; const short* B; const float* bias;
    void* dst; void* dst2; const unsigned short* qraw;
    int Mp, Mreal, mode, gofs, ostride, obase, nwaves;
};
struct GemmDesc5 { GemmDesc d[5]; };

// modes: 0 lrelu -> bf16 [p][Mp]; 1 proj -> [g][p][ostride] (+obase); 3 wp -> bf16 [p][160] + fp32 [p][144];
//        4 gelu -> bf16 [p][Mp]; 5 wm2 -> + residual -> d_out [m][4096]
template <int TM, int TN, int BM, int KP>
__global__ __launch_bounds__(256) void gemm_kernel(GemmDesc5 gd)
{
    const GemmDesc d = gd.d[blockIdx.z];
    const int wid = blockIdx.x * 4 + (threadIdx.x >> 6);
    if (wid >= d.nwaves) return;
    const int lane = threadIdx.x & 63;
    const int tiles_m = d.Mp / (16 * TM);
    const int m0 = (wid % tiles_m) * (16 * TM);
    const int p0 = (wid / tiles_m) * (16 * TN);
    const int ar = lane & 15;
    const int kq = (lane >> 4) * 8;

    f32x4v acc[TM][TN];
#pragma unroll
    for (int i = 0; i < TM; ++i)
#pragma unroll
        for (int j = 0; j < TN; ++j) acc[i][j] = (f32x4v){0.f, 0.f, 0.f, 0.f};

#pragma unroll
    for (int k0 = 0; k0 < KP; k0 += 32) {
        bf16x8v a[TM], b[TN];
#pragma unroll
        for (int i = 0; i < TM; ++i)
            a[i] = *(const bf16x8v*)(d.A + (size_t)(m0 + i * 16 + ar) * KP + k0 + kq);
        if (BM == 0) {
#pragma unroll
            for (int j = 0; j < TN; ++j)
                b[j] = *(const bf16x8v*)(d.B + (size_t)(p0 + j * 16 + ar) * KP + k0 + kq);
        } else {
            const int tap = k0 >> 6;
            const int cc = (k0 & 63) + kq;
            const int dy = tap / 3 - 1, dx = tap % 3 - 1;
#pragma unroll
            for (int j = 0; j < TN; ++j) {
                const int pix = p0 + j * 16 + ar;
                const int yy = (pix >> 6) + dy, xx = (pix & 63) + dx;
                const bool ok = ((unsigned)yy < 64u) & ((unsigned)xx < 64u);
                const int np = min(max(yy, 0), 63) * 64 + min(max(xx, 0), 63);
                bf16x8v bv = *(const bf16x8v*)(d.B + (size_t)np * 64 + cc);
                if (!ok) bv = (bf16x8v)(short)0;
                b[j] = bv;
            }
        }
#pragma unroll
        for (int i = 0; i < TM; ++i)
#pragma unroll
            for (int j = 0; j < TN; ++j)
                acc[i][j] = __builtin_amdgcn_mfma_f32_16x16x32_bf16(a[i], b[j], acc[i][j], 0, 0, 0);
    }

    const int isbf = (d.mode == 5) ? detect_bf16(d.qraw) : 0;
#pragma unroll
    for (int i = 0; i < TM; ++i) {
#pragma unroll
        for (int j = 0; j < TN; ++j) {
            const int pcol = p0 + j * 16 + (lane & 15);
            const int mb = m0 + i * 16 + (lane >> 4) * 4;
            float vv[4];
#pragma unroll
            for (int r = 0; r < 4; ++r) {
                const int m = mb + r;
                vv[r] = acc[i][j][r];
                if (m < d.Mreal) vv[r] += d.bias[m];
            }
            if (d.mode == 0) {
#pragma unroll
                for (int r = 0; r < 4; ++r) vv[r] = (vv[r] >= 0.f) ? vv[r] : 0.1f * vv[r];
                uint2 u;
                u.x = (unsigned)f2bu(vv[0]) | ((unsigned)f2bu(vv[1]) << 16);
                u.y = (unsigned)f2bu(vv[2]) | ((unsigned)f2bu(vv[3]) << 16);
                *(uint2*)((unsigned short*)d.dst + (size_t)pcol * d.Mp + mb) = u;
            } else if (d.mode == 1) {
                const int g = mb / 24 + d.gofs;
                uint2 u;
                u.x = (unsigned)f2bu(vv[0]) | ((unsigned)f2bu(vv[1]) << 16);
                u.y = (unsigned)f2bu(vv[2]) | ((unsigned)f2bu(vv[3]) << 16);
                *(uint2*)((unsigned short*)d.dst +
                          ((size_t)g * NPIX + pcol) * d.ostride + (mb % 24) + d.obase) = u;
            } else if (d.mode == 3) {
                uint2 u;
                u.x = (unsigned)f2bu(vv[0]) | ((unsigned)f2bu(vv[1]) << 16);
                u.y = (unsigned)f2bu(vv[2]) | ((unsigned)f2bu(vv[3]) << 16);
                *(uint2*)((unsigned short*)d.dst + (size_t)pcol * 160 + mb) = u;
                if (mb < 144)
                    *(float4*)((float*)d.dst2 + (size_t)pcol * 144 + mb) =
                        make_float4(vv[0], vv[1], vv[2], vv[3]);
            } else if (d.mode == 4) {
#pragma unroll
                for (int r = 0; r < 4; ++r)
                    vv[r] = 0.5f * vv[r] * (1.f + erff(vv[r] * 0.70710678118654752f));
                uint2 u;
                u.x = (unsigned)f2bu(vv[0]) | ((unsigned)f2bu(vv[1]) << 16);
                u.y = (unsigned)f2bu(vv[2]) | ((unsigned)f2bu(vv[3]) << 16);
                *(uint2*)((unsigned short*)d.dst + (size_t)pcol * d.Mp + mb) = u;
            } else { // 5
#pragma unroll
                for (int r = 0; r < 4; ++r) {
                    const int m = mb + r;
                    if (m < 144) {
                        float v = vv[r] + ((float*)d.dst2)[(size_t)pcol * 144 + m];
                        if (isbf) ((unsigned short*)d.dst)[(size_t)m * NPIX + pcol] = f2bu(v);
                        else      ((float*)d.dst)[(size_t)m * NPIX + pcol] = v;
                    }
                }
            }
        }
    }
}

// ---------------- conv6: static-unrolled ----------------
__global__ __launch_bounds__(256) void conv6_kernel(const short* __restrict__ YF,
                                                    const float* __restrict__ cw,
                                                    float* __restrict__ py, float* __restrict__ px)
{
    const int p = blockIdx.x * 256 + threadIdx.x;
    const int o0 = blockIdx.y * 16;
    const uint4* yrow = (const uint4*)(YF + (size_t)p * 64);
    const float* wb = cw + OF_WO6 + o0 * 64;

    float acc[16];
#pragma unroll
    for (int j = 0; j < 16; ++j) acc[j] = cw[OF_BO6 + o0 + j];

#pragma unroll
    for (int c = 0; c < 8; ++c) {
        uint4 u = yrow[c];
        float a0 = __uint_as_float(u.x << 16);
        float a1 = __uint_as_float(u.x & 0xFFFF0000u);
        float a2 = __uint_as_float(u.y << 16);
        float a3 = __uint_as_float(u.y & 0xFFFF0000u);
        float a4 = __uint_as_float(u.z << 16);
        float a5 = __uint_as_float(u.z & 0xFFFF0000u);
        float a6 = __uint_as_float(u.w << 16);
        float a7 = __uint_as_float(u.w & 0xFFFF0000u);
#pragma unroll
        for (int j = 0; j < 16; ++j) {
            const float* wr = wb + j * 64 + c * 8;
            acc[j] += a0 * wr[0] + a1 * wr[1] + a2 * wr[2] + a3 * wr[3]
                    + a4 * wr[4] + a5 * wr[5] + a6 * wr[6] + a7 * wr[7];
        }
    }

    const float f_y = cw[OF_FL0 + NPIX + p];
    const float f_x = cw[OF_FL0 + p];
    const float yf = (float)(p >> 6), xf = (float)(p & 63);
#pragma unroll
    for (int j = 0; j < 16; ++j) {
        int o = o0 + j;
        float val = 10.f * tanhf(acc[j]);
        int s = o >> 1;
        int a_idx = s % 9;
        if ((o & 1) == 0) py[s * NPIX + p] = val + f_y + (float)(a_idx / 3 - 1) + yf;
        else              px[s * NPIX + p] = val + f_x + (float)(a_idx % 3 - 1) + xf;
    }
}

// ---------------- attention: single-pass online softmax, interleaved KV -----------------
__device__ __forceinline__ float dot12(const bf16* __restrict__ row, const float* qv) {
    const uint2* s = (const uint2*)row;
    float d = 0.f;
#pragma unroll
    for (int c = 0; c < 3; ++c) {
        uint2 u = s[c];
        d += qv[c * 4 + 0] * __uint_as_float(u.x << 16);
        d += qv[c * 4 + 1] * __uint_as_float(u.x & 0xFFFF0000u);
        d += qv[c * 4 + 2] * __uint_as_float(u.y << 16);
        d += qv[c * 4 + 3] * __uint_as_float(u.y & 0xFFFF0000u);
    }
    return d;
}
__device__ __forceinline__ void acc12(float* ov, const bf16* __restrict__ row, float f) {
    const uint2* s = (const uint2*)row;
#pragma unroll
    for (int c = 0; c < 3; ++c) {
        uint2 u = s[c];
        ov[c * 4 + 0] += f * __uint_as_float(u.x << 16);
        ov[c * 4 + 1] += f * __uint_as_float(u.x & 0xFFFF0000u);
        ov[c * 4 + 2] += f * __uint_as_float(u.y << 16);
        ov[c * 4 + 3] += f * __uint_as_float(u.y & 0xFFFF0000u);
    }
}

__global__ __launch_bounds__(256) void attn_kernel(
    const bf16* __restrict__ qp, const bf16* __restrict__ kv,
    const float* __restrict__ py, const float* __restrict__ px,
    unsigned short* __restrict__ att)
{
    const int t = blockIdx.x * 256 + threadIdx.x;
    const int ch = t & 1;
    const int clip = (t >> 1) & 1;
    const int sh = (t >> 2) & 1;
    const int pp = t >> 3;
    const int m = pp >> 12;
    const int p = pp & 4095;

    float qv[12];
    {
        const uint2* s = (const uint2*)(qp + (size_t)(m * 4096 + p) * 24 + ch * 12);
#pragma unroll
        for (int c = 0; c < 3; ++c) {
            uint2 u = s[c];
            qv[c * 4 + 0] = __uint_as_float(u.x << 16);
            qv[c * 4 + 1] = __uint_as_float(u.x & 0xFFFF0000u);
            qv[c * 4 + 2] = __uint_as_float(u.y << 16);
            qv[c * 4 + 3] = __uint_as_float(u.y & 0xFFFF0000u);
        }
    }

    const int gidx = clip * 12 + m;
    const bf16* kvb = kv + (size_t)gidx * 4096 * 48 + ch * 12;   // K at +0, V at +24
    const int sbase = gidx * 9;
    const int a0 = sh ? 5 : 0;
    const int na = sh ? 4 : 5;

    float mxL = -1e30f, sumL = 0.f;
    float ov[12];
#pragma unroll
    for (int j = 0; j < 12; ++j) ov[j] = 0.f;

    // ROLLED loop (runtime bound) — caps in-flight loads, keeps VGPR low.
    for (int i = 0; i < na; ++i) {
        const int a = a0 + i;
        const float fy = py[(sbase + a) * NPIX + p];
        const float fx = px[(sbase + a) * NPIX + p];
        const float y0f = floorf(fy), x0f = floorf(fx);
        const float wy = fy - y0f, wx = fx - x0f;
        const int iy = (int)y0f, ix = (int)x0f;
        const float vy0 = ((unsigned)iy < 64u) ? 1.f : 0.f;
        const float vy1 = ((unsigned)(iy + 1) < 64u) ? 1.f : 0.f;
        const float vx0 = ((unsigned)ix < 64u) ? 1.f : 0.f;
        const float vx1 = ((unsigned)(ix + 1) < 64u) ? 1.f : 0.f;
        const int iy0 = min(max(iy, 0), 63), iy1 = min(max(iy + 1, 0), 63);
        const int ix0 = min(max(ix, 0), 63), ix1 = min(max(ix + 1, 0), 63);
        const float w0 = (1.f - wy) * (1.f - wx) * vy0 * vx0;
        const float w1 = (1.f - wy) * wx * vy0 * vx1;
        const float w2 = wy * (1.f - wx) * vy1 * vx0;
        const float w3 = wy * wx * vy1 * vx1;
        const int n0 = iy0 * 64 + ix0, n1 = iy0 * 64 + ix1;
        const int n2 = iy1 * 64 + ix0, n3 = iy1 * 64 + ix1;
        float part = w0 * dot12(kvb + (size_t)n0 * 48, qv)
                   + w1 * dot12(kvb + (size_t)n1 * 48, qv)
                   + w2 * dot12(kvb + (size_t)n2 * 48, qv)
                   + w3 * dot12(kvb + (size_t)n3 * 48, qv);
        float full = part + __shfl_xor(part, 1, 64);
        float e = full * 0.20412414523193154f;
        float newmx = fmaxf(mxL, e);
        float r = __expf(mxL - newmx);
        float ee = __expf(e - newmx);
        mxL = newmx;
        sumL = sumL * r + ee;
#pragma unroll
        for (int j = 0; j < 12; ++j) ov[j] *= r;
        acc12(ov, kvb + (size_t)n0 * 48 + 24, ee * w0);
        acc12(ov, kvb + (size_t)n1 * 48 + 24, ee * w1);
        acc12(ov, kvb + (size_t)n2 * 48 + 24, ee * w2);
        acc12(ov, kvb + (size_t)n3 * 48 + 24, ee * w3);
    }

    // exact flash-style combine across team (bit1=clip via xor 2, bit2=sh via xor 4)
    float M = fmaxf(mxL, __shfl_xor(mxL, 4, 64));
    M = fmaxf(M, __shfl_xor(M, 2, 64));
    const float sc = __expf(mxL - M);
    float s = sumL * sc;
    s += __shfl_xor(s, 4, 64);
    s += __shfl_xor(s, 2, 64);
    const float inv = 1.f / s;
#pragma unroll
    for (int j = 0; j < 12; ++j) {
        float v = ov[j] * sc;
        v += __shfl_xor(v, 4, 64);
        v += __shfl_xor(v, 2, 64);
        ov[j] = v * inv;
    }
    if (clip == 0 && sh == 0) {
        unsigned short* ab = att + (size_t)p * 288 + m * 24 + ch * 12;
#pragma unroll
        for (int c = 0; c < 3; ++c) {
            uint2 u;
            u.x = (unsigned)f2bu(ov[c * 4 + 0]) | ((unsigned)f2bu(ov[c * 4 + 1]) << 16);
            u.y = (unsigned)f2bu(ov[c * 4 + 2]) | ((unsigned)f2bu(ov[c * 4 + 3]) << 16);
            ((uint2*)ab)[c] = u;
        }
    }
}

// ---------------- diagnostic ----------------
__global__ void diag_kernel(float* __restrict__ out, int n, float v)
{
    int i = blockIdx.x * 256 + threadIdx.x;
    if (i < n) out[i] = (i == 0 ? v : 0.f);
}

extern "C" void kernel_launch(void* const* d_in, const int* in_sizes, int n_in,
                              void* d_out, int out_size, void* d_ws, size_t ws_size,
                              hipStream_t stream)
{
    const size_t REQUIRED = 75000000;
    if (ws_size < REQUIRED) {
        float code = 1000.0f + (float)(ws_size >> 20);
        diag_kernel<<<dim3((out_size + 255) / 256), 256, 0, stream>>>((float*)d_out, out_size, code);
        return;
    }

    char* W = (char*)d_ws;
    short* wsS = (short*)W;
    float* cw = (float*)(W + 64);

    short* conv1w = wsS + 1000000;
    short* conv3w[4] = { wsS + 1028672, wsS + 1065536, wsS + 1102400, wsS + 1139264 };
    short* wqb = wsS + 1176128, *wkb = wsS + 1222208, *wvb = wsS + 1268288;
    short* wpS = wsS + 1314368, *wm1S = wsS + 1360448, *wm2S = wsS + 1406528;

    short* XS = (short*)(W + 16777216);
    short* X1 = (short*)(W + 25165824);
    bf16*  QP = (bf16*)(W + 33554432);
    bf16*  KV = (bf16*)(W + 36700160);   // [24][4096][48] interleaved K|V, 9.4 MB
    short* Y0 = (short*)(W + 50331648);
    short* Y1 = (short*)(W + 50855936);
    short* YF = (short*)(W + 51380224);
    float* PY = (float*)(W + 54525952);
    float* PX = (float*)(W + 58064896);
    unsigned short* ATT = (unsigned short*)(W + 62914560);
    short* OPM = (short*)(W + 67108864);
    float* O32 = (float*)(W + 68419584);
    short* M1  = (short*)(W + 71303168);

    const unsigned short* qraw = (const unsigned short*)d_in[0];

    // 1. convert (only consumed tensors) + stage + prepack (fused)
    CArgs ca;
    const int srcidx[14] = {8,10,12,14,16,17,18,20,22,24,26,28,30,5};
    const int dsto[14]   = {OF_BO1,OF_BO2,OF_BO3,OF_BO4,OF_BO5,OF_WO6,OF_BO6,
                            OF_BQ,OF_BK,OF_BV,OF_BP,OF_BM1,OF_BM2,OF_FL0};
    for (int i = 0; i < 14; ++i) {
        ca.src[i] = d_in[srcidx[i]];
        ca.dstoff[i] = dsto[i];
        ca.n[i] = in_sizes[srcidx[i]];
    }
    PPArgs pp;
    pp.j[0]  = { d_in[7],  1000000, 64, 448, 436, 64,  436, 0 };
    pp.j[1]  = { d_in[9],  1028672, 64, 576, 576, 64,  576, 2 };
    pp.j[2]  = { d_in[11], 1065536, 64, 576, 576, 64,  576, 2 };
    pp.j[3]  = { d_in[13], 1102400, 64, 576, 576, 64,  576, 2 };
    pp.j[4]  = { d_in[15], 1139264, 64, 576, 576, 64,  576, 2 };
    pp.j[5]  = { d_in[19], 1176128, 288, 160, 144, 288, 288, 1 };
    pp.j[6]  = { d_in[21], 1222208, 288, 160, 144, 288, 288, 1 };
    pp.j[7]  = { d_in[23], 1268288, 288, 160, 144, 288, 288, 1 };
    pp.j[8]  = { d_in[25], 1314368, 160, 288, 288, 144, 144, 1 };
    pp.j[9]  = { d_in[27], 1360448, 288, 160, 144, 288, 288, 1 };
    pp.j[10] = { d_in[29], 1406528, 160, 288, 288, 144, 144, 1 };
    misc_kernel<<<dim3(16, 39), 256, 0, stream>>>(ca, pp, d_in[0], d_in[1], d_in[2], d_in[3],
                                                  d_in[4], d_in[5], d_in[6], cw, XS, X1, wsS);

    // 2. proj x5 (one dispatch, KP=160 unrolled). Q->QP stride24; K->KV stride48+0; V->KV stride48+24
    GemmDesc5 g3;
    const short* Xz[5] = { XS, XS + 655360, XS + 1310720, XS + 1966080, XS + 2621440 };
    const short* Az[5] = { wqb, wkb, wkb, wvb, wvb };
    const float* Bz[5] = { cw + OF_BQ, cw + OF_BK, cw + OF_BK, cw + OF_BV, cw + OF_BV };
    bf16* Dz[5] = { QP, KV, KV, KV, KV };
    const int Gz[5] = { 0, 0, 12, 0, 12 };
    const int Oz[5] = { 24, 48, 48, 48, 48 };
    const int Bo[5] = { 0, 0, 0, 24, 24 };
    for (int z = 0; z < 5; ++z)
        g3.d[z] = { Az[z], Xz[z], Bz[z], Dz[z], nullptr, qraw, 288, 288, 1, Gz[z], Oz[z], Bo[z], 1152 };
    gemm_kernel<2, 2, 0, 160><<<dim3(288, 1, 5), 256, 0, stream>>>(g3);

    // 3. conv1 (KP=448)
    GemmDesc5 g1;
    g1.d[0] = { conv1w, X1, cw + OF_BO1, Y0, nullptr, qraw, 64, 64, 0, 0, 0, 0, 1024 };
    gemm_kernel<1, 1, 0, 448><<<dim3(256, 1, 1), 256, 0, stream>>>(g1);

    // 4-7. conv3 chain, implicit-im2col GEMMs (KP=576)
    const float* cb[4] = { cw + OF_BO2, cw + OF_BO3, cw + OF_BO4, cw + OF_BO5 };
    short* cin[4] = { Y0, Y1, Y0, Y1 };
    short* coutp[4] = { Y1, Y0, Y1, YF };
    for (int i = 0; i < 4; ++i) {
        GemmDesc5 gc;
        gc.d[0] = { conv3w[i], cin[i], cb[i], coutp[i], nullptr, qraw, 64, 64, 0, 0, 0, 0, 1024 };
        gemm_kernel<1, 1, 1, 576><<<dim3(256, 1, 1), 256, 0, stream>>>(gc);
    }

    // 8. conv6 -> py/px
    conv6_kernel<<<dim3(16, 27), 256, 0, stream>>>(YF, cw, PY, PX);

    // 9. attention (single-pass online softmax, interleaved KV)
    attn_kernel<<<dim3(1536), 256, 0, stream>>>(QP, KV, PY, PX, ATT);

    // 10. wp GEMM (KP=288)
    GemmDesc5 gwp;
    gwp.d[0] = { wpS, (const short*)ATT, cw + OF_BP, OPM, O32, qraw, 160, 144, 3, 0, 0, 0, 640 };
    gemm_kernel<2, 2, 0, 288><<<dim3(160, 1, 1), 256, 0, stream>>>(gwp);

    // 11. wm1 GEMM + gelu (KP=160)
    GemmDesc5 gm1;
    gm1.d[0] = { wm1S, OPM, cw + OF_BM1, M1, nullptr, qraw, 288, 288, 4, 0, 0, 0, 1152 };
    gemm_kernel<2, 2, 0, 160><<<dim3(288, 1, 1), 256, 0, stream>>>(gm1);

    // 12. wm2 GEMM + residual -> d_out (KP=288)
    GemmDesc5 gm2;
    gm2.d[0] = { wm2S, M1, cw + OF_BM2, d_out, O32, qraw, 160, 144, 5, 0, 0, 0, 640 };
    gemm_kernel<2, 2, 0, 288><<<dim3(160, 1, 1), 256, 0, stream>>>(gm2);
}

// Round 15
// 285.827 us; speedup vs baseline: 1.0068x; 1.0068x over previous
//
#include <hip/hip_runtime.h>
#include <hip/hip_bf16.h>
#include <math.h>

typedef __hip_bfloat16 bf16;
typedef __attribute__((ext_vector_type(8))) short bf16x8v;
typedef __attribute__((ext_vector_type(4))) float f32x4v;

#define NPIX 4096

__device__ __forceinline__ float b2f(bf16 v) { return __bfloat162float(v); }
__device__ __forceinline__ unsigned short f2bu(float f) {
    bf16 h = __float2bfloat16(f);
    return *(unsigned short*)&h;
}
__device__ __forceinline__ int detect_bf16(const unsigned short* __restrict__ qraw) {
    int lane = threadIdx.x & 63;
    unsigned short u = qraw[lane * 2];
    int e = (u >> 7) & 0xFF;
    unsigned long long ball = __ballot(e >= 100 && e <= 135);
    return __popcll(ball) > 32;
}
__device__ __forceinline__ float rdval(const void* s, int idx, int isbf) {
    return isbf ? b2f(((const bf16*)s)[idx]) : ((const float*)s)[idx];
}

// cw element offsets
#define OF_WO6 175680
#define OF_BO6 203328
#define OF_BO1 27904
#define OF_BO2 64832
#define OF_BO3 101760
#define OF_BO4 138688
#define OF_BO5 175616
#define OF_BQ  245232
#define OF_BK  286992
#define OF_BV  328752
#define OF_BP  370512
#define OF_BM1 412128
#define OF_BM2 453888
#define OF_FL0 454032

// ---------------- fused: convert(14) + stage_pm(10) + stage_x1(4) + prepack(11) ----------------
struct CArgs { const void* src[14]; int dstoff[14]; int n[14]; };
struct PPJob { const void* src; int dstS; int Mp, Kp, kr, mr, sstride, kind; };
struct PPArgs { PPJob j[11]; };

__global__ void misc_kernel(CArgs a, PPArgs pa, const void* __restrict__ q,
                            const void* __restrict__ k, const void* __restrict__ v,
                            const void* __restrict__ vp0, const void* __restrict__ vp1,
                            const void* __restrict__ fl0, const void* __restrict__ fl1,
                            float* __restrict__ cw, short* __restrict__ XS,
                            short* __restrict__ X1, short* __restrict__ wsS)
{
    const int isbf = detect_bf16((const unsigned short*)q);
    const int y = blockIdx.y;
    if (y < 14) {
        const int n = a.n[y];
        float* d = cw + a.dstoff[y];
        if (isbf) {
            const bf16* s = (const bf16*)a.src[y];
            for (int i = blockIdx.x * 256 + threadIdx.x; i < n; i += 256 * 16) d[i] = b2f(s[i]);
        } else {
            const float* s = (const float*)a.src[y];
            for (int i = blockIdx.x * 256 + threadIdx.x; i < n; i += 256 * 16) d[i] = s[i];
        }
    } else if (y < 24) {
        const int job = y - 14;
        const int z = job >> 1, half = job & 1;
        const int p = blockIdx.x * 256 + threadIdx.x;
        const void* srcs[5] = { q, k, k, v, v };
        const int clips[5] = { 0, 0, 1, 0, 1 };
        const size_t co = (size_t)clips[z] * 144 * NPIX;
        short* row = XS + (size_t)z * 655360 + (size_t)p * 160;
        for (int c0 = half * 72; c0 < half * 72 + 72; c0 += 8) {
            unsigned short h[8];
            if (isbf) {
                const bf16* s = (const bf16*)srcs[z] + co;
#pragma unroll
                for (int i = 0; i < 8; ++i) h[i] = f2bu(b2f(s[(size_t)(c0 + i) * NPIX + p]));
            } else {
                const float* s = (const float*)srcs[z] + co;
#pragma unroll
                for (int i = 0; i < 8; ++i) h[i] = f2bu(s[(size_t)(c0 + i) * NPIX + p]);
            }
            uint4 u;
            u.x = (unsigned)h[0] | ((unsigned)h[1] << 16);
            u.y = (unsigned)h[2] | ((unsigned)h[3] << 16);
            u.z = (unsigned)h[4] | ((unsigned)h[5] << 16);
            u.w = (unsigned)h[6] | ((unsigned)h[7] << 16);
            *(uint4*)(row + c0) = u;
        }
        if (half == 1) {
            uint4 zz; zz.x = zz.y = zz.z = zz.w = 0u;
            *(uint4*)(row + 144) = zz;
            *(uint4*)(row + 152) = zz;
        }
    } else if (y < 28) {
        const int sec = y - 24;
        const int p = blockIdx.x * 256 + threadIdx.x;
        short* row = X1 + (size_t)p * 448;
        if (sec < 3) {
            const void* srcs[3] = { q, vp0, vp1 };
            const int cbase = sec * 144;
            for (int c0 = 0; c0 < 144; c0 += 8) {
                unsigned short h[8];
                if (isbf) {
                    const bf16* s = (const bf16*)srcs[sec];
#pragma unroll
                    for (int i = 0; i < 8; ++i) h[i] = f2bu(b2f(s[(size_t)(c0 + i) * NPIX + p]));
                } else {
                    const float* s = (const float*)srcs[sec];
#pragma unroll
                    for (int i = 0; i < 8; ++i) h[i] = f2bu(s[(size_t)(c0 + i) * NPIX + p]);
                }
                uint4 u;
                u.x = (unsigned)h[0] | ((unsigned)h[1] << 16);
                u.y = (unsigned)h[2] | ((unsigned)h[3] << 16);
                u.z = (unsigned)h[4] | ((unsigned)h[5] << 16);
                u.w = (unsigned)h[6] | ((unsigned)h[7] << 16);
                *(uint4*)(row + cbase + c0) = u;
            }
        } else {
            unsigned short h[4];
            if (isbf) {
                const bf16* f0 = (const bf16*)fl0;
                const bf16* f1 = (const bf16*)fl1;
                h[0] = f2bu(b2f(f0[p]));
                h[1] = f2bu(b2f(f0[NPIX + p]));
                h[2] = f2bu(b2f(f1[p]));
                h[3] = f2bu(b2f(f1[NPIX + p]));
            } else {
                const float* f0 = (const float*)fl0;
                const float* f1 = (const float*)fl1;
                h[0] = f2bu(f0[p]);
                h[1] = f2bu(f0[NPIX + p]);
                h[2] = f2bu(f1[p]);
                h[3] = f2bu(f1[NPIX + p]);
            }
            uint4 u;
            u.x = (unsigned)h[0] | ((unsigned)h[1] << 16);
            u.y = (unsigned)h[2] | ((unsigned)h[3] << 16);
            u.z = 0u; u.w = 0u;
            *(uint4*)(row + 432) = u;
            uint4 zz; zz.x = zz.y = zz.z = zz.w = 0u;
            *(uint4*)(row + 440) = zz;
        }
    } else {
        PPJob J = pa.j[y - 28];
        const int tot = J.Mp * J.Kp;
        for (int e = blockIdx.x * 256 + threadIdx.x; e < tot; e += 256 * 16) {
            int m = e / J.Kp, kk = e - m * J.Kp;
            float vv = 0.f;
            if (J.kind == 0) { if (kk < J.kr) vv = rdval(J.src, m * J.sstride + kk, isbf); }
            else if (J.kind == 1) { if (kk < J.kr && m < J.mr) vv = rdval(J.src, kk * J.sstride + m, isbf); }
            else { int c = kk & 63, tap = kk >> 6; if (kk < J.kr) vv = rdval(J.src, m * J.sstride + c * 9 + tap, isbf); }
            wsS[J.dstS + e] = (short)f2bu(vv);
        }
    }
}

// ---------------- MFMA GEMM (KP compile-time -> fully unrolled K-loop) ----------------
struct GemmDesc {
    const short* A; const short* B; const float* bias;
    void* dst; void* dst2; const unsigned short* qraw;
    int Mp, Mreal, mode, gofs, ostride, obase, nwaves;
};
struct GemmDesc5 { GemmDesc d[5]; };

template <int TM, int TN, int BM, int KP>
__global__ __launch_bounds__(256) void gemm_kernel(GemmDesc5 gd)
{
    const GemmDesc d = gd.d[blockIdx.z];
    const int wid = blockIdx.x * 4 + (threadIdx.x >> 6);
    if (wid >= d.nwaves) return;
    const int lane = threadIdx.x & 63;
    const int tiles_m = d.Mp / (16 * TM);
    const int m0 = (wid % tiles_m) * (16 * TM);
    const int p0 = (wid / tiles_m) * (16 * TN);
    const int ar = lane & 15;
    const int kq = (lane >> 4) * 8;

    f32x4v acc[TM][TN];
#pragma unroll
    for (int i = 0; i < TM; ++i)
#pragma unroll
        for (int j = 0; j < TN; ++j) acc[i][j] = (f32x4v){0.f, 0.f, 0.f, 0.f};

#pragma unroll
    for (int k0 = 0; k0 < KP; k0 += 32) {
        bf16x8v a[TM], b[TN];
#pragma unroll
        for (int i = 0; i < TM; ++i)
            a[i] = *(const bf16x8v*)(d.A + (size_t)(m0 + i * 16 + ar) * KP + k0 + kq);
        if (BM == 0) {
#pragma unroll
            for (int j = 0; j < TN; ++j)
                b[j] = *(const bf16x8v*)(d.B + (size_t)(p0 + j * 16 + ar) * KP + k0 + kq);
        } else {
            const int tap = k0 >> 6;
            const int cc = (k0 & 63) + kq;
            const int dy = tap / 3 - 1, dx = tap % 3 - 1;
#pragma unroll
            for (int j = 0; j < TN; ++j) {
                const int pix = p0 + j * 16 + ar;
                const int yy = (pix >> 6) + dy, xx = (pix & 63) + dx;
                const bool ok = ((unsigned)yy < 64u) & ((unsigned)xx < 64u);
                const int np = min(max(yy, 0), 63) * 64 + min(max(xx, 0), 63);
                bf16x8v bv = *(const bf16x8v*)(d.B + (size_t)np * 64 + cc);
                if (!ok) bv = (bf16x8v)(short)0;
                b[j] = bv;
            }
        }
#pragma unroll
        for (int i = 0; i < TM; ++i)
#pragma unroll
            for (int j = 0; j < TN; ++j)
                acc[i][j] = __builtin_amdgcn_mfma_f32_16x16x32_bf16(a[i], b[j], acc[i][j], 0, 0, 0);
    }

    const int isbf = (d.mode == 5) ? detect_bf16(d.qraw) : 0;
#pragma unroll
    for (int i = 0; i < TM; ++i) {
#pragma unroll
        for (int j = 0; j < TN; ++j) {
            const int pcol = p0 + j * 16 + (lane & 15);
            const int mb = m0 + i * 16 + (lane >> 4) * 4;
            float vv[4];
#pragma unroll
            for (int r = 0; r < 4; ++r) {
                const int m = mb + r;
                vv[r] = acc[i][j][r];
                if (m < d.Mreal) vv[r] += d.bias[m];
            }
            if (d.mode == 0) {
#pragma unroll
                for (int r = 0; r < 4; ++r) vv[r] = (vv[r] >= 0.f) ? vv[r] : 0.1f * vv[r];
                uint2 u;
                u.x = (unsigned)f2bu(vv[0]) | ((unsigned)f2bu(vv[1]) << 16);
                u.y = (unsigned)f2bu(vv[2]) | ((unsigned)f2bu(vv[3]) << 16);
                *(uint2*)((unsigned short*)d.dst + (size_t)pcol * d.Mp + mb) = u;
            } else if (d.mode == 1) {
                const int g = mb / 24 + d.gofs;
                uint2 u;
                u.x = (unsigned)f2bu(vv[0]) | ((unsigned)f2bu(vv[1]) << 16);
                u.y = (unsigned)f2bu(vv[2]) | ((unsigned)f2bu(vv[3]) << 16);
                *(uint2*)((unsigned short*)d.dst +
                          ((size_t)g * NPIX + pcol) * d.ostride + (mb % 24) + d.obase) = u;
            } else if (d.mode == 3) {
                uint2 u;
                u.x = (unsigned)f2bu(vv[0]) | ((unsigned)f2bu(vv[1]) << 16);
                u.y = (unsigned)f2bu(vv[2]) | ((unsigned)f2bu(vv[3]) << 16);
                *(uint2*)((unsigned short*)d.dst + (size_t)pcol * 160 + mb) = u;
                if (mb < 144)
                    *(float4*)((float*)d.dst2 + (size_t)pcol * 144 + mb) =
                        make_float4(vv[0], vv[1], vv[2], vv[3]);
            } else if (d.mode == 4) {
#pragma unroll
                for (int r = 0; r < 4; ++r)
                    vv[r] = 0.5f * vv[r] * (1.f + erff(vv[r] * 0.70710678118654752f));
                uint2 u;
                u.x = (unsigned)f2bu(vv[0]) | ((unsigned)f2bu(vv[1]) << 16);
                u.y = (unsigned)f2bu(vv[2]) | ((unsigned)f2bu(vv[3]) << 16);
                *(uint2*)((unsigned short*)d.dst + (size_t)pcol * d.Mp + mb) = u;
            } else { // 5
#pragma unroll
                for (int r = 0; r < 4; ++r) {
                    const int m = mb + r;
                    if (m < 144) {
                        float v = vv[r] + ((float*)d.dst2)[(size_t)pcol * 144 + m];
                        if (isbf) ((unsigned short*)d.dst)[(size_t)m * NPIX + pcol] = f2bu(v);
                        else      ((float*)d.dst)[(size_t)m * NPIX + pcol] = v;
                    }
                }
            }
        }
    }
}

// ---------------- conv6: static-unrolled, writes interleaved PYX float2 -------------------
__global__ __launch_bounds__(256) void conv6_kernel(const short* __restrict__ YF,
                                                    const float* __restrict__ cw,
                                                    float* __restrict__ pyx)
{
    const int p = blockIdx.x * 256 + threadIdx.x;
    const int o0 = blockIdx.y * 16;
    const uint4* yrow = (const uint4*)(YF + (size_t)p * 64);
    const float* wb = cw + OF_WO6 + o0 * 64;

    float acc[16];
#pragma unroll
    for (int j = 0; j < 16; ++j) acc[j] = cw[OF_BO6 + o0 + j];

#pragma unroll
    for (int c = 0; c < 8; ++c) {
        uint4 u = yrow[c];
        float a0 = __uint_as_float(u.x << 16);
        float a1 = __uint_as_float(u.x & 0xFFFF0000u);
        float a2 = __uint_as_float(u.y << 16);
        float a3 = __uint_as_float(u.y & 0xFFFF0000u);
        float a4 = __uint_as_float(u.z << 16);
        float a5 = __uint_as_float(u.z & 0xFFFF0000u);
        float a6 = __uint_as_float(u.w << 16);
        float a7 = __uint_as_float(u.w & 0xFFFF0000u);
#pragma unroll
        for (int j = 0; j < 16; ++j) {
            const float* wr = wb + j * 64 + c * 8;
            acc[j] += a0 * wr[0] + a1 * wr[1] + a2 * wr[2] + a3 * wr[3]
                    + a4 * wr[4] + a5 * wr[5] + a6 * wr[6] + a7 * wr[7];
        }
    }

    const float f_y = cw[OF_FL0 + NPIX + p];
    const float f_x = cw[OF_FL0 + p];
    const float yf = (float)(p >> 6), xf = (float)(p & 63);
#pragma unroll
    for (int j = 0; j < 16; j += 2) {
        const int s = (o0 + j) >> 1;            // o0+j even, o0+j+1 odd -> same s
        const int a_idx = s % 9;
        float vy = 10.f * tanhf(acc[j]);
        float vx = 10.f * tanhf(acc[j + 1]);
        float2 o;
        o.x = vy + f_y + (float)(a_idx / 3 - 1) + yf;
        o.y = vx + f_x + (float)(a_idx % 3 - 1) + xf;
        *(float2*)(pyx + 2 * ((size_t)s * NPIX + p)) = o;
    }
}

// ---------------- attention: r10-style two-pass, interleaved KV + PYX --------------------
__device__ __forceinline__ float dot12(const bf16* __restrict__ row, const float* qv) {
    const uint2* s = (const uint2*)row;
    float d = 0.f;
#pragma unroll
    for (int c = 0; c < 3; ++c) {
        uint2 u = s[c];
        d += qv[c * 4 + 0] * __uint_as_float(u.x << 16);
        d += qv[c * 4 + 1] * __uint_as_float(u.x & 0xFFFF0000u);
        d += qv[c * 4 + 2] * __uint_as_float(u.y << 16);
        d += qv[c * 4 + 3] * __uint_as_float(u.y & 0xFFFF0000u);
    }
    return d;
}
__device__ __forceinline__ void acc12(float* ov, const bf16* __restrict__ row, float f) {
    const uint2* s = (const uint2*)row;
#pragma unroll
    for (int c = 0; c < 3; ++c) {
        uint2 u = s[c];
        ov[c * 4 + 0] += f * __uint_as_float(u.x << 16);
        ov[c * 4 + 1] += f * __uint_as_float(u.x & 0xFFFF0000u);
        ov[c * 4 + 2] += f * __uint_as_float(u.y << 16);
        ov[c * 4 + 3] += f * __uint_as_float(u.y & 0xFFFF0000u);
    }
}

__global__ __launch_bounds__(256) void attn_kernel(
    const bf16* __restrict__ qp, const bf16* __restrict__ kv,
    const float* __restrict__ pyx, unsigned short* __restrict__ att)
{
    const int t = blockIdx.x * 256 + threadIdx.x;
    const int ch = t & 1;
    const int clip = (t >> 1) & 1;
    const int sh = (t >> 2) & 1;
    const int pp = t >> 3;
    const int m = pp >> 12;
    const int p = pp & 4095;

    float qv[12];
    {
        const uint2* s = (const uint2*)(qp + (size_t)(m * 4096 + p) * 24 + ch * 12);
#pragma unroll
        for (int c = 0; c < 3; ++c) {
            uint2 u = s[c];
            qv[c * 4 + 0] = __uint_as_float(u.x << 16);
            qv[c * 4 + 1] = __uint_as_float(u.x & 0xFFFF0000u);
            qv[c * 4 + 2] = __uint_as_float(u.y << 16);
            qv[c * 4 + 3] = __uint_as_float(u.y & 0xFFFF0000u);
        }
    }

    const int gidx = clip * 12 + m;
    const bf16* kvb = kv + (size_t)gidx * 4096 * 48 + ch * 12;   // K at +0, V at +24
    const int sbase = gidx * 9;
    const int a0 = sh ? 5 : 0;
    const int na = sh ? 4 : 5;

    float e[5], fyv[5], fxv[5];
    float mx = -1e30f;
#pragma unroll
    for (int i = 0; i < 5; ++i) {
        e[i] = -1e30f; fyv[i] = 0.f; fxv[i] = 0.f;
        if (i < na) {
            const int a = a0 + i;
            const float2 f2v = *(const float2*)(pyx + 2 * ((size_t)(sbase + a) * NPIX + p));
            const float fy = f2v.x, fx = f2v.y;
            fyv[i] = fy; fxv[i] = fx;
            const float y0 = floorf(fy), x0 = floorf(fx);
            const float wy = fy - y0, wx = fx - x0;
            const int iy = (int)y0, ix = (int)x0;
            const float w00 = (1.f - wy) * (1.f - wx), w01 = (1.f - wy) * wx;
            const float w10 = wy * (1.f - wx), w11 = wy * wx;
            float part = 0.f;
            if ((unsigned)iy < 64u) {
                const bf16* rr = kvb + (size_t)(iy * 64) * 48;
                if ((unsigned)ix < 64u)       part += w00 * dot12(rr + ix * 48, qv);
                if ((unsigned)(ix + 1) < 64u) part += w01 * dot12(rr + (ix + 1) * 48, qv);
            }
            if ((unsigned)(iy + 1) < 64u) {
                const bf16* rr = kvb + (size_t)((iy + 1) * 64) * 48;
                if ((unsigned)ix < 64u)       part += w10 * dot12(rr + ix * 48, qv);
                if ((unsigned)(ix + 1) < 64u) part += w11 * dot12(rr + (ix + 1) * 48, qv);
            }
            float full = part + __shfl_xor(part, 1, 64);
            e[i] = full * 0.20412414523193154f;
            mx = fmaxf(mx, e[i]);
        }
    }
    mx = fmaxf(mx, __shfl_xor(mx, 4, 64));
    mx = fmaxf(mx, __shfl_xor(mx, 2, 64));
    float sum = 0.f;
#pragma unroll
    for (int i = 0; i < 5; ++i) {
        if (i < na) { e[i] = __expf(e[i] - mx); sum += e[i]; }
    }
    sum += __shfl_xor(sum, 4, 64);
    sum += __shfl_xor(sum, 2, 64);
    const float inv = 1.f / sum;

    float ov[12];
#pragma unroll
    for (int j = 0; j < 12; ++j) ov[j] = 0.f;

#pragma unroll
    for (int i = 0; i < 5; ++i) {
        if (i < na) {
            const float wa = e[i] * inv;
            const float fy = fyv[i], fx = fxv[i];
            const float y0 = floorf(fy), x0 = floorf(fx);
            const float wy = fy - y0, wx = fx - x0;
            const int iy = (int)y0, ix = (int)x0;
            if ((unsigned)iy < 64u) {
                const bf16* rr = kvb + (size_t)(iy * 64) * 48 + 24;
                if ((unsigned)ix < 64u)       acc12(ov, rr + ix * 48, wa * (1.f - wy) * (1.f - wx));
                if ((unsigned)(ix + 1) < 64u) acc12(ov, rr + (ix + 1) * 48, wa * (1.f - wy) * wx);
            }
            if ((unsigned)(iy + 1) < 64u) {
                const bf16* rr = kvb + (size_t)((iy + 1) * 64) * 48 + 24;
                if ((unsigned)ix < 64u)       acc12(ov, rr + ix * 48, wa * wy * (1.f - wx));
                if ((unsigned)(ix + 1) < 64u) acc12(ov, rr + (ix + 1) * 48, wa * wy * wx);
            }
        }
    }
#pragma unroll
    for (int j = 0; j < 12; ++j) {
        ov[j] += __shfl_xor(ov[j], 4, 64);
        ov[j] += __shfl_xor(ov[j], 2, 64);
    }
    if (clip == 0 && sh == 0) {
        unsigned short* ab = att + (size_t)p * 288 + m * 24 + ch * 12;
#pragma unroll
        for (int c = 0; c < 3; ++c) {
            uint2 u;
            u.x = (unsigned)f2bu(ov[c * 4 + 0]) | ((unsigned)f2bu(ov[c * 4 + 1]) << 16);
            u.y = (unsigned)f2bu(ov[c * 4 + 2]) | ((unsigned)f2bu(ov[c * 4 + 3]) << 16);
            ((uint2*)ab)[c] = u;
        }
    }
}

// ---------------- diagnostic ----------------
__global__ void diag_kernel(float* __restrict__ out, int n, float v)
{
    int i = blockIdx.x * 256 + threadIdx.x;
    if (i < n) out[i] = (i == 0 ? v : 0.f);
}

extern "C" void kernel_launch(void* const* d_in, const int* in_sizes, int n_in,
                              void* d_out, int out_size, void* d_ws, size_t ws_size,
                              hipStream_t stream)
{
    const size_t REQUIRED = 75000000;
    if (ws_size < REQUIRED) {
        float code = 1000.0f + (float)(ws_size >> 20);
        diag_kernel<<<dim3((out_size + 255) / 256), 256, 0, stream>>>((float*)d_out, out_size, code);
        return;
    }

    char* W = (char*)d_ws;
    short* wsS = (short*)W;
    float* cw = (float*)(W + 64);

    short* conv1w = wsS + 1000000;
    short* conv3w[4] = { wsS + 1028672, wsS + 1065536, wsS + 1102400, wsS + 1139264 };
    short* wqb = wsS + 1176128, *wkb = wsS + 1222208, *wvb = wsS + 1268288;
    short* wpS = wsS + 1314368, *wm1S = wsS + 1360448, *wm2S = wsS + 1406528;

    short* XS = (short*)(W + 16777216);
    short* X1 = (short*)(W + 25165824);
    bf16*  QP = (bf16*)(W + 33554432);
    bf16*  KV = (bf16*)(W + 36700160);   // [24][4096][48] interleaved K|V, 9.4 MB
    short* Y0 = (short*)(W + 50331648);
    short* Y1 = (short*)(W + 50855936);
    short* YF = (short*)(W + 51380224);
    float* PYX = (float*)(W + 54525952); // [216][4096][2] interleaved y,x fp32, 7.1 MB
    unsigned short* ATT = (unsigned short*)(W + 62914560);
    short* OPM = (short*)(W + 67108864);
    float* O32 = (float*)(W + 68419584);
    short* M1  = (short*)(W + 71303168);

    const unsigned short* qraw = (const unsigned short*)d_in[0];

    // 1. convert (only consumed tensors) + stage + prepack (fused)
    CArgs ca;
    const int srcidx[14] = {8,10,12,14,16,17,18,20,22,24,26,28,30,5};
    const int dsto[14]   = {OF_BO1,OF_BO2,OF_BO3,OF_BO4,OF_BO5,OF_WO6,OF_BO6,
                            OF_BQ,OF_BK,OF_BV,OF_BP,OF_BM1,OF_BM2,OF_FL0};
    for (int i = 0; i < 14; ++i) {
        ca.src[i] = d_in[srcidx[i]];
        ca.dstoff[i] = dsto[i];
        ca.n[i] = in_sizes[srcidx[i]];
    }
    PPArgs pp;
    pp.j[0]  = { d_in[7],  1000000, 64, 448, 436, 64,  436, 0 };
    pp.j[1]  = { d_in[9],  1028672, 64, 576, 576, 64,  576, 2 };
    pp.j[2]  = { d_in[11], 1065536, 64, 576, 576, 64,  576, 2 };
    pp.j[3]  = { d_in[13], 1102400, 64, 576, 576, 64,  576, 2 };
    pp.j[4]  = { d_in[15], 1139264, 64, 576, 576, 64,  576, 2 };
    pp.j[5]  = { d_in[19], 1176128, 288, 160, 144, 288, 288, 1 };
    pp.j[6]  = { d_in[21], 1222208, 288, 160, 144, 288, 288, 1 };
    pp.j[7]  = { d_in[23], 1268288, 288, 160, 144, 288, 288, 1 };
    pp.j[8]  = { d_in[25], 1314368, 160, 288, 288, 144, 144, 1 };
    pp.j[9]  = { d_in[27], 1360448, 288, 160, 144, 288, 288, 1 };
    pp.j[10] = { d_in[29], 1406528, 160, 288, 288, 144, 144, 1 };
    misc_kernel<<<dim3(16, 39), 256, 0, stream>>>(ca, pp, d_in[0], d_in[1], d_in[2], d_in[3],
                                                  d_in[4], d_in[5], d_in[6], cw, XS, X1, wsS);

    // 2. proj x5 (one dispatch, KP=160 unrolled). Q->QP stride24; K->KV stride48+0; V->KV stride48+24
    GemmDesc5 g3;
    const short* Xz[5] = { XS, XS + 655360, XS + 1310720, XS + 1966080, XS + 2621440 };
    const short* Az[5] = { wqb, wkb, wkb, wvb, wvb };
    const float* Bz[5] = { cw + OF_BQ, cw + OF_BK, cw + OF_BK, cw + OF_BV, cw + OF_BV };
    bf16* Dz[5] = { QP, KV, KV, KV, KV };
    const int Gz[5] = { 0, 0, 12, 0, 12 };
    const int Oz[5] = { 24, 48, 48, 48, 48 };
    const int Bo[5] = { 0, 0, 0, 24, 24 };
    for (int z = 0; z < 5; ++z)
        g3.d[z] = { Az[z], Xz[z], Bz[z], Dz[z], nullptr, qraw, 288, 288, 1, Gz[z], Oz[z], Bo[z], 1152 };
    gemm_kernel<2, 2, 0, 160><<<dim3(288, 1, 5), 256, 0, stream>>>(g3);

    // 3. conv1 (KP=448)
    GemmDesc5 g1;
    g1.d[0] = { conv1w, X1, cw + OF_BO1, Y0, nullptr, qraw, 64, 64, 0, 0, 0, 0, 1024 };
    gemm_kernel<1, 1, 0, 448><<<dim3(256, 1, 1), 256, 0, stream>>>(g1);

    // 4-7. conv3 chain, implicit-im2col GEMMs (KP=576)
    const float* cb[4] = { cw + OF_BO2, cw + OF_BO3, cw + OF_BO4, cw + OF_BO5 };
    short* cin[4] = { Y0, Y1, Y0, Y1 };
    short* coutp[4] = { Y1, Y0, Y1, YF };
    for (int i = 0; i < 4; ++i) {
        GemmDesc5 gc;
        gc.d[0] = { conv3w[i], cin[i], cb[i], coutp[i], nullptr, qraw, 64, 64, 0, 0, 0, 0, 1024 };
        gemm_kernel<1, 1, 1, 576><<<dim3(256, 1, 1), 256, 0, stream>>>(gc);
    }

    // 8. conv6 -> PYX (interleaved)
    conv6_kernel<<<dim3(16, 27), 256, 0, stream>>>(YF, cw, PYX);

    // 9. attention (two-pass, interleaved KV, PYX float2)
    attn_kernel<<<dim3(1536), 256, 0, stream>>>(QP, KV, PYX, ATT);

    // 10. wp GEMM (KP=288)
    GemmDesc5 gwp;
    gwp.d[0] = { wpS, (const short*)ATT, cw + OF_BP, OPM, O32, qraw, 160, 144, 3, 0, 0, 0, 640 };
    gemm_kernel<2, 2, 0, 288><<<dim3(160, 1, 1), 256, 0, stream>>>(gwp);

    // 11. wm1 GEMM + gelu (KP=160)
    GemmDesc5 gm1;
    gm1.d[0] = { wm1S, OPM, cw + OF_BM1, M1, nullptr, qraw, 288, 288, 4, 0, 0, 0, 1152 };
    gemm_kernel<2, 2, 0, 160><<<dim3(288, 1, 1), 256, 0, stream>>>(gm1);

    // 12. wm2 GEMM + residual -> d_out (KP=288)
    GemmDesc5 gm2;
    gm2.d[0] = { wm2S, M1, cw + OF_BM2, d_out, O32, qraw, 160, 144, 5, 0, 0, 0, 640 };
    gemm_kernel<2, 2, 0, 288><<<dim3(160, 1, 1), 256, 0, stream>>>(gm2);
}

// Round 16
// 274.390 us; speedup vs baseline: 1.0488x; 1.0417x over previous
//
#include <hip/hip_runtime.h>
#include <hip/hip_bf16.h>
#include <math.h>

typedef __hip_bfloat16 bf16;
typedef __attribute__((ext_vector_type(8))) short bf16x8v;
typedef __attribute__((ext_vector_type(4))) float f32x4v;

#define NPIX 4096

__device__ __forceinline__ float b2f(bf16 v) { return __bfloat162float(v); }
__device__ __forceinline__ unsigned short f2bu(float f) {
    bf16 h = __float2bfloat16(f);
    return *(unsigned short*)&h;
}
__device__ __forceinline__ int detect_bf16(const unsigned short* __restrict__ qraw) {
    int lane = threadIdx.x & 63;
    unsigned short u = qraw[lane * 2];
    int e = (u >> 7) & 0xFF;
    unsigned long long ball = __ballot(e >= 100 && e <= 135);
    return __popcll(ball) > 32;
}
__device__ __forceinline__ float rdval(const void* s, int idx, int isbf) {
    return isbf ? b2f(((const bf16*)s)[idx]) : ((const float*)s)[idx];
}

// cw element offsets
#define OF_WO6 175680
#define OF_BO6 203328
#define OF_BO1 27904
#define OF_BO2 64832
#define OF_BO3 101760
#define OF_BO4 138688
#define OF_BO5 175616
#define OF_BQ  245232
#define OF_BK  286992
#define OF_BV  328752
#define OF_BP  370512
#define OF_BM1 412128
#define OF_BM2 453888
#define OF_FL0 454032

// ---------------- fused: convert(14) + stage_pm(10) + stage_x1(4) + prepack(11) ----------------
struct CArgs { const void* src[14]; int dstoff[14]; int n[14]; };
struct PPJob { const void* src; int dstS; int Mp, Kp, kr, mr, sstride, kind; };
struct PPArgs { PPJob j[11]; };

__global__ void misc_kernel(CArgs a, PPArgs pa, const void* __restrict__ q,
                            const void* __restrict__ k, const void* __restrict__ v,
                            const void* __restrict__ vp0, const void* __restrict__ vp1,
                            const void* __restrict__ fl0, const void* __restrict__ fl1,
                            float* __restrict__ cw, short* __restrict__ XS,
                            short* __restrict__ X1, short* __restrict__ wsS)
{
    const int isbf = detect_bf16((const unsigned short*)q);
    const int y = blockIdx.y;
    if (y < 14) {
        const int n = a.n[y];
        float* d = cw + a.dstoff[y];
        if (isbf) {
            const bf16* s = (const bf16*)a.src[y];
            for (int i = blockIdx.x * 256 + threadIdx.x; i < n; i += 256 * 16) d[i] = b2f(s[i]);
        } else {
            const float* s = (const float*)a.src[y];
            for (int i = blockIdx.x * 256 + threadIdx.x; i < n; i += 256 * 16) d[i] = s[i];
        }
    } else if (y < 24) {
        const int job = y - 14;
        const int z = job >> 1, half = job & 1;
        const int p = blockIdx.x * 256 + threadIdx.x;
        const void* srcs[5] = { q, k, k, v, v };
        const int clips[5] = { 0, 0, 1, 0, 1 };
        const size_t co = (size_t)clips[z] * 144 * NPIX;
        short* row = XS + (size_t)z * 655360 + (size_t)p * 160;
        for (int c0 = half * 72; c0 < half * 72 + 72; c0 += 8) {
            unsigned short h[8];
            if (isbf) {
                const bf16* s = (const bf16*)srcs[z] + co;
#pragma unroll
                for (int i = 0; i < 8; ++i) h[i] = f2bu(b2f(s[(size_t)(c0 + i) * NPIX + p]));
            } else {
                const float* s = (const float*)srcs[z] + co;
#pragma unroll
                for (int i = 0; i < 8; ++i) h[i] = f2bu(s[(size_t)(c0 + i) * NPIX + p]);
            }
            uint4 u;
            u.x = (unsigned)h[0] | ((unsigned)h[1] << 16);
            u.y = (unsigned)h[2] | ((unsigned)h[3] << 16);
            u.z = (unsigned)h[4] | ((unsigned)h[5] << 16);
            u.w = (unsigned)h[6] | ((unsigned)h[7] << 16);
            *(uint4*)(row + c0) = u;
        }
        if (half == 1) {
            uint4 zz; zz.x = zz.y = zz.z = zz.w = 0u;
            *(uint4*)(row + 144) = zz;
            *(uint4*)(row + 152) = zz;
        }
    } else if (y < 28) {
        const int sec = y - 24;
        const int p = blockIdx.x * 256 + threadIdx.x;
        short* row = X1 + (size_t)p * 448;
        if (sec < 3) {
            const void* srcs[3] = { q, vp0, vp1 };
            const int cbase = sec * 144;
            for (int c0 = 0; c0 < 144; c0 += 8) {
                unsigned short h[8];
                if (isbf) {
                    const bf16* s = (const bf16*)srcs[sec];
#pragma unroll
                    for (int i = 0; i < 8; ++i) h[i] = f2bu(b2f(s[(size_t)(c0 + i) * NPIX + p]));
                } else {
                    const float* s = (const float*)srcs[sec];
#pragma unroll
                    for (int i = 0; i < 8; ++i) h[i] = f2bu(s[(size_t)(c0 + i) * NPIX + p]);
                }
                uint4 u;
                u.x = (unsigned)h[0] | ((unsigned)h[1] << 16);
                u.y = (unsigned)h[2] | ((unsigned)h[3] << 16);
                u.z = (unsigned)h[4] | ((unsigned)h[5] << 16);
                u.w = (unsigned)h[6] | ((unsigned)h[7] << 16);
                *(uint4*)(row + cbase + c0) = u;
            }
        } else {
            unsigned short h[4];
            if (isbf) {
                const bf16* f0 = (const bf16*)fl0;
                const bf16* f1 = (const bf16*)fl1;
                h[0] = f2bu(b2f(f0[p]));
                h[1] = f2bu(b2f(f0[NPIX + p]));
                h[2] = f2bu(b2f(f1[p]));
                h[3] = f2bu(b2f(f1[NPIX + p]));
            } else {
                const float* f0 = (const float*)fl0;
                const float* f1 = (const float*)fl1;
                h[0] = f2bu(f0[p]);
                h[1] = f2bu(f0[NPIX + p]);
                h[2] = f2bu(f1[p]);
                h[3] = f2bu(f1[NPIX + p]);
            }
            uint4 u;
            u.x = (unsigned)h[0] | ((unsigned)h[1] << 16);
            u.y = (unsigned)h[2] | ((unsigned)h[3] << 16);
            u.z = 0u; u.w = 0u;
            *(uint4*)(row + 432) = u;
            uint4 zz; zz.x = zz.y = zz.z = zz.w = 0u;
            *(uint4*)(row + 440) = zz;
        }
    } else {
        PPJob J = pa.j[y - 28];
        const int tot = J.Mp * J.Kp;
        for (int e = blockIdx.x * 256 + threadIdx.x; e < tot; e += 256 * 16) {
            int m = e / J.Kp, kk = e - m * J.Kp;
            float vv = 0.f;
            if (J.kind == 0) { if (kk < J.kr) vv = rdval(J.src, m * J.sstride + kk, isbf); }
            else if (J.kind == 1) { if (kk < J.kr && m < J.mr) vv = rdval(J.src, kk * J.sstride + m, isbf); }
            else { int c = kk & 63, tap = kk >> 6; if (kk < J.kr) vv = rdval(J.src, m * J.sstride + c * 9 + tap, isbf); }
            wsS[J.dstS + e] = (short)f2bu(vv);
        }
    }
}

// ---------------- MFMA GEMM (KP compile-time -> fully unrolled K-loop) ----------------
struct GemmDesc {
    const short* A; const short* B; const float* bias;
    void* dst; void* dst2; const unsigned short* qraw;
    int Mp, Mreal, mode, gofs, ostride, obase, nwaves;
};
struct GemmDesc5 { GemmDesc d[5]; };

template <int TM, int TN, int BM, int KP>
__global__ __launch_bounds__(256) void gemm_kernel(GemmDesc5 gd)
{
    const GemmDesc d = gd.d[blockIdx.z];
    const int wid = blockIdx.x * 4 + (threadIdx.x >> 6);
    if (wid >= d.nwaves) return;
    const int lane = threadIdx.x & 63;
    const int tiles_m = d.Mp / (16 * TM);
    const int m0 = (wid % tiles_m) * (16 * TM);
    const int p0 = (wid / tiles_m) * (16 * TN);
    const int ar = lane & 15;
    const int kq = (lane >> 4) * 8;

    f32x4v acc[TM][TN];
#pragma unroll
    for (int i = 0; i < TM; ++i)
#pragma unroll
        for (int j = 0; j < TN; ++j) acc[i][j] = (f32x4v){0.f, 0.f, 0.f, 0.f};

#pragma unroll
    for (int k0 = 0; k0 < KP; k0 += 32) {
        bf16x8v a[TM], b[TN];
#pragma unroll
        for (int i = 0; i < TM; ++i)
            a[i] = *(const bf16x8v*)(d.A + (size_t)(m0 + i * 16 + ar) * KP + k0 + kq);
        if (BM == 0) {
#pragma unroll
            for (int j = 0; j < TN; ++j)
                b[j] = *(const bf16x8v*)(d.B + (size_t)(p0 + j * 16 + ar) * KP + k0 + kq);
        } else {
            const int tap = k0 >> 6;
            const int cc = (k0 & 63) + kq;
            const int dy = tap / 3 - 1, dx = tap % 3 - 1;
#pragma unroll
            for (int j = 0; j < TN; ++j) {
                const int pix = p0 + j * 16 + ar;
                const int yy = (pix >> 6) + dy, xx = (pix & 63) + dx;
                const bool ok = ((unsigned)yy < 64u) & ((unsigned)xx < 64u);
                const int np = min(max(yy, 0), 63) * 64 + min(max(xx, 0), 63);
                bf16x8v bv = *(const bf16x8v*)(d.B + (size_t)np * 64 + cc);
                if (!ok) bv = (bf16x8v)(short)0;
                b[j] = bv;
            }
        }
#pragma unroll
        for (int i = 0; i < TM; ++i)
#pragma unroll
            for (int j = 0; j < TN; ++j)
                acc[i][j] = __builtin_amdgcn_mfma_f32_16x16x32_bf16(a[i], b[j], acc[i][j], 0, 0, 0);
    }

    const int isbf = (d.mode == 5) ? detect_bf16(d.qraw) : 0;
#pragma unroll
    for (int i = 0; i < TM; ++i) {
#pragma unroll
        for (int j = 0; j < TN; ++j) {
            const int pcol = p0 + j * 16 + (lane & 15);
            const int mb = m0 + i * 16 + (lane >> 4) * 4;
            float vv[4];
#pragma unroll
            for (int r = 0; r < 4; ++r) {
                const int m = mb + r;
                vv[r] = acc[i][j][r];
                if (m < d.Mreal) vv[r] += d.bias[m];
            }
            if (d.mode == 0) {
#pragma unroll
                for (int r = 0; r < 4; ++r) vv[r] = (vv[r] >= 0.f) ? vv[r] : 0.1f * vv[r];
                uint2 u;
                u.x = (unsigned)f2bu(vv[0]) | ((unsigned)f2bu(vv[1]) << 16);
                u.y = (unsigned)f2bu(vv[2]) | ((unsigned)f2bu(vv[3]) << 16);
                *(uint2*)((unsigned short*)d.dst + (size_t)pcol * d.Mp + mb) = u;
            } else if (d.mode == 1) {
                const int g = mb / 24 + d.gofs;
                uint2 u;
                u.x = (unsigned)f2bu(vv[0]) | ((unsigned)f2bu(vv[1]) << 16);
                u.y = (unsigned)f2bu(vv[2]) | ((unsigned)f2bu(vv[3]) << 16);
                *(uint2*)((unsigned short*)d.dst +
                          ((size_t)g * NPIX + pcol) * d.ostride + (mb % 24) + d.obase) = u;
            } else if (d.mode == 3) {
                uint2 u;
                u.x = (unsigned)f2bu(vv[0]) | ((unsigned)f2bu(vv[1]) << 16);
                u.y = (unsigned)f2bu(vv[2]) | ((unsigned)f2bu(vv[3]) << 16);
                *(uint2*)((unsigned short*)d.dst + (size_t)pcol * 160 + mb) = u;
                if (mb < 144)
                    *(float4*)((float*)d.dst2 + (size_t)pcol * 144 + mb) =
                        make_float4(vv[0], vv[1], vv[2], vv[3]);
            } else if (d.mode == 4) {
#pragma unroll
                for (int r = 0; r < 4; ++r)
                    vv[r] = 0.5f * vv[r] * (1.f + erff(vv[r] * 0.70710678118654752f));
                uint2 u;
                u.x = (unsigned)f2bu(vv[0]) | ((unsigned)f2bu(vv[1]) << 16);
                u.y = (unsigned)f2bu(vv[2]) | ((unsigned)f2bu(vv[3]) << 16);
                *(uint2*)((unsigned short*)d.dst + (size_t)pcol * d.Mp + mb) = u;
            } else { // 5
#pragma unroll
                for (int r = 0; r < 4; ++r) {
                    const int m = mb + r;
                    if (m < 144) {
                        float v = vv[r] + ((float*)d.dst2)[(size_t)pcol * 144 + m];
                        if (isbf) ((unsigned short*)d.dst)[(size_t)m * NPIX + pcol] = f2bu(v);
                        else      ((float*)d.dst)[(size_t)m * NPIX + pcol] = v;
                    }
                }
            }
        }
    }
}

// ---------------- conv6: static-unrolled, writes interleaved PYX float2 -------------------
__global__ __launch_bounds__(256) void conv6_kernel(const short* __restrict__ YF,
                                                    const float* __restrict__ cw,
                                                    float* __restrict__ pyx)
{
    const int p = blockIdx.x * 256 + threadIdx.x;
    const int o0 = blockIdx.y * 16;
    const uint4* yrow = (const uint4*)(YF + (size_t)p * 64);
    const float* wb = cw + OF_WO6 + o0 * 64;

    float acc[16];
#pragma unroll
    for (int j = 0; j < 16; ++j) acc[j] = cw[OF_BO6 + o0 + j];

#pragma unroll
    for (int c = 0; c < 8; ++c) {
        uint4 u = yrow[c];
        float a0 = __uint_as_float(u.x << 16);
        float a1 = __uint_as_float(u.x & 0xFFFF0000u);
        float a2 = __uint_as_float(u.y << 16);
        float a3 = __uint_as_float(u.y & 0xFFFF0000u);
        float a4 = __uint_as_float(u.z << 16);
        float a5 = __uint_as_float(u.z & 0xFFFF0000u);
        float a6 = __uint_as_float(u.w << 16);
        float a7 = __uint_as_float(u.w & 0xFFFF0000u);
#pragma unroll
        for (int j = 0; j < 16; ++j) {
            const float* wr = wb + j * 64 + c * 8;
            acc[j] += a0 * wr[0] + a1 * wr[1] + a2 * wr[2] + a3 * wr[3]
                    + a4 * wr[4] + a5 * wr[5] + a6 * wr[6] + a7 * wr[7];
        }
    }

    const float f_y = cw[OF_FL0 + NPIX + p];
    const float f_x = cw[OF_FL0 + p];
    const float yf = (float)(p >> 6), xf = (float)(p & 63);
#pragma unroll
    for (int j = 0; j < 16; j += 2) {
        const int s = (o0 + j) >> 1;
        const int a_idx = s % 9;
        float vy = 10.f * tanhf(acc[j]);
        float vx = 10.f * tanhf(acc[j + 1]);
        float2 o;
        o.x = vy + f_y + (float)(a_idx / 3 - 1) + yf;
        o.y = vx + f_x + (float)(a_idx % 3 - 1) + xf;
        *(float2*)(pyx + 2 * ((size_t)s * NPIX + p)) = o;
    }
}

// ---------------- attention: two-pass, 16-thread teams, separate K/V, PYX ----------------
__device__ __forceinline__ float dot12(const bf16* __restrict__ row, const float* qv) {
    const uint2* s = (const uint2*)row;
    float d = 0.f;
#pragma unroll
    for (int c = 0; c < 3; ++c) {
        uint2 u = s[c];
        d += qv[c * 4 + 0] * __uint_as_float(u.x << 16);
        d += qv[c * 4 + 1] * __uint_as_float(u.x & 0xFFFF0000u);
        d += qv[c * 4 + 2] * __uint_as_float(u.y << 16);
        d += qv[c * 4 + 3] * __uint_as_float(u.y & 0xFFFF0000u);
    }
    return d;
}
__device__ __forceinline__ void acc12(float* ov, const bf16* __restrict__ row, float f) {
    const uint2* s = (const uint2*)row;
#pragma unroll
    for (int c = 0; c < 3; ++c) {
        uint2 u = s[c];
        ov[c * 4 + 0] += f * __uint_as_float(u.x << 16);
        ov[c * 4 + 1] += f * __uint_as_float(u.x & 0xFFFF0000u);
        ov[c * 4 + 2] += f * __uint_as_float(u.y << 16);
        ov[c * 4 + 3] += f * __uint_as_float(u.y & 0xFFFF0000u);
    }
}

__global__ __launch_bounds__(256) void attn_kernel(
    const bf16* __restrict__ qp, const bf16* __restrict__ kp,
    const bf16* __restrict__ vp, const float* __restrict__ pyx,
    unsigned short* __restrict__ att)
{
    const int t = blockIdx.x * 256 + threadIdx.x;
    const int ch = t & 1;
    const int clip = (t >> 1) & 1;
    const int sq = (t >> 2) & 3;
    const int pp = t >> 4;
    const int m = pp / 4096;
    const int p = pp & 4095;

    float qv[12];
    {
        const uint2* s = (const uint2*)(qp + (size_t)(m * 4096 + p) * 24 + ch * 12);
#pragma unroll
        for (int c = 0; c < 3; ++c) {
            uint2 u = s[c];
            qv[c * 4 + 0] = __uint_as_float(u.x << 16);
            qv[c * 4 + 1] = __uint_as_float(u.x & 0xFFFF0000u);
            qv[c * 4 + 2] = __uint_as_float(u.y << 16);
            qv[c * 4 + 3] = __uint_as_float(u.y & 0xFFFF0000u);
        }
    }

    const int gidx = clip * 12 + m;
    const bf16* kb = kp + (size_t)gidx * 4096 * 24 + ch * 12;
    const bf16* vb = vp + (size_t)gidx * 4096 * 24 + ch * 12;
    const int sbase = gidx * 9;
    const int a0 = (sq == 0) ? 0 : (sq * 2 + 1);   // 0,3,5,7
    const int na = (sq == 0) ? 3 : 2;

    float e[3], fyv[3], fxv[3];
    float mx = -1e30f;
#pragma unroll
    for (int i = 0; i < 3; ++i) {
        e[i] = -1e30f; fyv[i] = 0.f; fxv[i] = 0.f;
        if (i < na) {
            const int a = a0 + i;
            const float2 f2v = *(const float2*)(pyx + 2 * ((size_t)(sbase + a) * NPIX + p));
            const float fy = f2v.x, fx = f2v.y;
            fyv[i] = fy; fxv[i] = fx;
            const float y0 = floorf(fy), x0 = floorf(fx);
            const float wy = fy - y0, wx = fx - x0;
            const int iy = (int)y0, ix = (int)x0;
            const float w00 = (1.f - wy) * (1.f - wx), w01 = (1.f - wy) * wx;
            const float w10 = wy * (1.f - wx), w11 = wy * wx;
            float part = 0.f;
            if ((unsigned)iy < 64u) {
                const bf16* rr = kb + (size_t)(iy * 64) * 24;
                if ((unsigned)ix < 64u)       part += w00 * dot12(rr + ix * 24, qv);
                if ((unsigned)(ix + 1) < 64u) part += w01 * dot12(rr + (ix + 1) * 24, qv);
            }
            if ((unsigned)(iy + 1) < 64u) {
                const bf16* rr = kb + (size_t)((iy + 1) * 64) * 24;
                if ((unsigned)ix < 64u)       part += w10 * dot12(rr + ix * 24, qv);
                if ((unsigned)(ix + 1) < 64u) part += w11 * dot12(rr + (ix + 1) * 24, qv);
            }
            float full = part + __shfl_xor(part, 1, 64);
            e[i] = full * 0.20412414523193154f;
            mx = fmaxf(mx, e[i]);
        }
    }
    mx = fmaxf(mx, __shfl_xor(mx, 8, 64));
    mx = fmaxf(mx, __shfl_xor(mx, 4, 64));
    mx = fmaxf(mx, __shfl_xor(mx, 2, 64));
    float sum = 0.f;
#pragma unroll
    for (int i = 0; i < 3; ++i) {
        if (i < na) { e[i] = __expf(e[i] - mx); sum += e[i]; }
    }
    sum += __shfl_xor(sum, 8, 64);
    sum += __shfl_xor(sum, 4, 64);
    sum += __shfl_xor(sum, 2, 64);
    const float inv = 1.f / sum;

    float ov[12];
#pragma unroll
    for (int j = 0; j < 12; ++j) ov[j] = 0.f;

#pragma unroll
    for (int i = 0; i < 3; ++i) {
        if (i < na) {
            const float wa = e[i] * inv;
            const float fy = fyv[i], fx = fxv[i];
            const float y0 = floorf(fy), x0 = floorf(fx);
            const float wy = fy - y0, wx = fx - x0;
            const int iy = (int)y0, ix = (int)x0;
            if ((unsigned)iy < 64u) {
                const bf16* rr = vb + (size_t)(iy * 64) * 24;
                if ((unsigned)ix < 64u)       acc12(ov, rr + ix * 24, wa * (1.f - wy) * (1.f - wx));
                if ((unsigned)(ix + 1) < 64u) acc12(ov, rr + (ix + 1) * 24, wa * (1.f - wy) * wx);
            }
            if ((unsigned)(iy + 1) < 64u) {
                const bf16* rr = vb + (size_t)((iy + 1) * 64) * 24;
                if ((unsigned)ix < 64u)       acc12(ov, rr + ix * 24, wa * wy * (1.f - wx));
                if ((unsigned)(ix + 1) < 64u) acc12(ov, rr + (ix + 1) * 24, wa * wy * wx);
            }
        }
    }
#pragma unroll
    for (int j = 0; j < 12; ++j) {
        ov[j] += __shfl_xor(ov[j], 8, 64);
        ov[j] += __shfl_xor(ov[j], 4, 64);
        ov[j] += __shfl_xor(ov[j], 2, 64);
    }
    if (clip == 0 && sq == 0) {
        unsigned short* ab = att + (size_t)p * 288 + m * 24 + ch * 12;
#pragma unroll
        for (int c = 0; c < 3; ++c) {
            uint2 u;
            u.x = (unsigned)f2bu(ov[c * 4 + 0]) | ((unsigned)f2bu(ov[c * 4 + 1]) << 16);
            u.y = (unsigned)f2bu(ov[c * 4 + 2]) | ((unsigned)f2bu(ov[c * 4 + 3]) << 16);
            ((uint2*)ab)[c] = u;
        }
    }
}

// ---------------- diagnostic ----------------
__global__ void diag_kernel(float* __restrict__ out, int n, float v)
{
    int i = blockIdx.x * 256 + threadIdx.x;
    if (i < n) out[i] = (i == 0 ? v : 0.f);
}

extern "C" void kernel_launch(void* const* d_in, const int* in_sizes, int n_in,
                              void* d_out, int out_size, void* d_ws, size_t ws_size,
                              hipStream_t stream)
{
    const size_t REQUIRED = 75000000;
    if (ws_size < REQUIRED) {
        float code = 1000.0f + (float)(ws_size >> 20);
        diag_kernel<<<dim3((out_size + 255) / 256), 256, 0, stream>>>((float*)d_out, out_size, code);
        return;
    }

    char* W = (char*)d_ws;
    short* wsS = (short*)W;
    float* cw = (float*)(W + 64);

    short* conv1w = wsS + 1000000;
    short* conv3w[4] = { wsS + 1028672, wsS + 1065536, wsS + 1102400, wsS + 1139264 };
    short* wqb = wsS + 1176128, *wkb = wsS + 1222208, *wvb = wsS + 1268288;
    short* wpS = wsS + 1314368, *wm1S = wsS + 1360448, *wm2S = wsS + 1406528;

    short* XS = (short*)(W + 16777216);
    short* X1 = (short*)(W + 25165824);
    bf16*  QP = (bf16*)(W + 33554432);
    bf16*  KP = (bf16*)(W + 36700160);
    bf16*  VP = (bf16*)(W + 41943040);
    short* Y0 = (short*)(W + 50331648);
    short* Y1 = (short*)(W + 50855936);
    short* YF = (short*)(W + 51380224);
    float* PYX = (float*)(W + 54525952); // [216][4096][2] interleaved y,x fp32
    unsigned short* ATT = (unsigned short*)(W + 62914560);
    short* OPM = (short*)(W + 67108864);
    float* O32 = (float*)(W + 68419584);
    short* M1  = (short*)(W + 71303168);

    const unsigned short* qraw = (const unsigned short*)d_in[0];

    // 1. convert (only consumed tensors) + stage + prepack (fused)
    CArgs ca;
    const int srcidx[14] = {8,10,12,14,16,17,18,20,22,24,26,28,30,5};
    const int dsto[14]   = {OF_BO1,OF_BO2,OF_BO3,OF_BO4,OF_BO5,OF_WO6,OF_BO6,
                            OF_BQ,OF_BK,OF_BV,OF_BP,OF_BM1,OF_BM2,OF_FL0};
    for (int i = 0; i < 14; ++i) {
        ca.src[i] = d_in[srcidx[i]];
        ca.dstoff[i] = dsto[i];
        ca.n[i] = in_sizes[srcidx[i]];
    }
    PPArgs pp;
    pp.j[0]  = { d_in[7],  1000000, 64, 448, 436, 64,  436, 0 };
    pp.j[1]  = { d_in[9],  1028672, 64, 576, 576, 64,  576, 2 };
    pp.j[2]  = { d_in[11], 1065536, 64, 576, 576, 64,  576, 2 };
    pp.j[3]  = { d_in[13], 1102400, 64, 576, 576, 64,  576, 2 };
    pp.j[4]  = { d_in[15], 1139264, 64, 576, 576, 64,  576, 2 };
    pp.j[5]  = { d_in[19], 1176128, 288, 160, 144, 288, 288, 1 };
    pp.j[6]  = { d_in[21], 1222208, 288, 160, 144, 288, 288, 1 };
    pp.j[7]  = { d_in[23], 1268288, 288, 160, 144, 288, 288, 1 };
    pp.j[8]  = { d_in[25], 1314368, 160, 288, 288, 144, 144, 1 };
    pp.j[9]  = { d_in[27], 1360448, 288, 160, 144, 288, 288, 1 };
    pp.j[10] = { d_in[29], 1406528, 160, 288, 288, 144, 144, 1 };
    misc_kernel<<<dim3(16, 39), 256, 0, stream>>>(ca, pp, d_in[0], d_in[1], d_in[2], d_in[3],
                                                  d_in[4], d_in[5], d_in[6], cw, XS, X1, wsS);

    // 2. proj x5 (one dispatch, KP=160 unrolled), separate QP/KP/VP (stride 24)
    GemmDesc5 g3;
    const short* Xz[5] = { XS, XS + 655360, XS + 1310720, XS + 1966080, XS + 2621440 };
    const short* Az[5] = { wqb, wkb, wkb, wvb, wvb };
    const float* Bz[5] = { cw + OF_BQ, cw + OF_BK, cw + OF_BK, cw + OF_BV, cw + OF_BV };
    bf16* Dz[5] = { QP, KP, KP, VP, VP };
    const int Gz[5] = { 0, 0, 12, 0, 12 };
    for (int z = 0; z < 5; ++z)
        g3.d[z] = { Az[z], Xz[z], Bz[z], Dz[z], nullptr, qraw, 288, 288, 1, Gz[z], 24, 0, 1152 };
    gemm_kernel<2, 2, 0, 160><<<dim3(288, 1, 5), 256, 0, stream>>>(g3);

    // 3. conv1 (KP=448)
    GemmDesc5 g1;
    g1.d[0] = { conv1w, X1, cw + OF_BO1, Y0, nullptr, qraw, 64, 64, 0, 0, 0, 0, 1024 };
    gemm_kernel<1, 1, 0, 448><<<dim3(256, 1, 1), 256, 0, stream>>>(g1);

    // 4-7. conv3 chain, implicit-im2col GEMMs (KP=576)
    const float* cb[4] = { cw + OF_BO2, cw + OF_BO3, cw + OF_BO4, cw + OF_BO5 };
    short* cin[4] = { Y0, Y1, Y0, Y1 };
    short* coutp[4] = { Y1, Y0, Y1, YF };
    for (int i = 0; i < 4; ++i) {
        GemmDesc5 gc;
        gc.d[0] = { conv3w[i], cin[i], cb[i], coutp[i], nullptr, qraw, 64, 64, 0, 0, 0, 0, 1024 };
        gemm_kernel<1, 1, 1, 576><<<dim3(256, 1, 1), 256, 0, stream>>>(gc);
    }

    // 8. conv6 -> PYX (interleaved)
    conv6_kernel<<<dim3(16, 27), 256, 0, stream>>>(YF, cw, PYX);

    // 9. attention (two-pass, 16-thread teams, separate K/V, PYX)
    attn_kernel<<<dim3(3072), 256, 0, stream>>>(QP, KP, VP, PYX, ATT);

    // 10. wp GEMM (KP=288)
    GemmDesc5 gwp;
    gwp.d[0] = { wpS, (const short*)ATT, cw + OF_BP, OPM, O32, qraw, 160, 144, 3, 0, 0, 0, 640 };
    gemm_kernel<2, 2, 0, 288><<<dim3(160, 1, 1), 256, 0, stream>>>(gwp);

    // 11. wm1 GEMM + gelu (KP=160)
    GemmDesc5 gm1;
    gm1.d[0] = { wm1S, OPM, cw + OF_BM1, M1, nullptr, qraw, 288, 288, 4, 0, 0, 0, 1152 };
    gemm_kernel<2, 2, 0, 160><<<dim3(288, 1, 1), 256, 0, stream>>>(gm1);

    // 12. wm2 GEMM + residual -> d_out (KP=288)
    GemmDesc5 gm2;
    gm2.d[0] = { wm2S, M1, cw + OF_BM2, d_out, O32, qraw, 160, 144, 5, 0, 0, 0, 640 };
    gemm_kernel<2, 2, 0, 288><<<dim3(160, 1, 1), 256, 0, stream>>>(gm2);
}

// Round 17
// 271.894 us; speedup vs baseline: 1.0584x; 1.0092x over previous
//
#include <hip/hip_runtime.h>
#include <hip/hip_bf16.h>
#include <math.h>

typedef __hip_bfloat16 bf16;
typedef __attribute__((ext_vector_type(8))) short bf16x8v;
typedef __attribute__((ext_vector_type(4))) float f32x4v;

#define NPIX 4096

__device__ __forceinline__ float b2f(bf16 v) { return __bfloat162float(v); }
__device__ __forceinline__ unsigned short f2bu(float f) {
    bf16 h = __float2bfloat16(f);
    return *(unsigned short*)&h;
}
__device__ __forceinline__ int detect_bf16(const unsigned short* __restrict__ qraw) {
    int lane = threadIdx.x & 63;
    unsigned short u = qraw[lane * 2];
    int e = (u >> 7) & 0xFF;
    unsigned long long ball = __ballot(e >= 100 && e <= 135);
    return __popcll(ball) > 32;
}
__device__ __forceinline__ float rdval(const void* s, int idx, int isbf) {
    return isbf ? b2f(((const bf16*)s)[idx]) : ((const float*)s)[idx];
}

// cw element offsets
#define OF_WO6 175680
#define OF_BO6 203328
#define OF_BO1 27904
#define OF_BO2 64832
#define OF_BO3 101760
#define OF_BO4 138688
#define OF_BO5 175616
#define OF_BQ  245232
#define OF_BK  286992
#define OF_BV  328752
#define OF_BP  370512
#define OF_BM1 412128
#define OF_BM2 453888
#define OF_FL0 454032

// ---------------- fused: convert(14) + stage_pm(10) + stage_x1(4) + prepack(11) ----------------
struct CArgs { const void* src[14]; int dstoff[14]; int n[14]; };
struct PPJob { const void* src; int dstS; int Mp, Kp, kr, mr, sstride, kind; };
struct PPArgs { PPJob j[11]; };

__global__ void misc_kernel(CArgs a, PPArgs pa, const void* __restrict__ q,
                            const void* __restrict__ k, const void* __restrict__ v,
                            const void* __restrict__ vp0, const void* __restrict__ vp1,
                            const void* __restrict__ fl0, const void* __restrict__ fl1,
                            float* __restrict__ cw, short* __restrict__ XS,
                            short* __restrict__ X1, short* __restrict__ wsS)
{
    const int isbf = detect_bf16((const unsigned short*)q);
    const int y = blockIdx.y;
    if (y < 14) {
        const int n = a.n[y];
        float* d = cw + a.dstoff[y];
        if (isbf) {
            const bf16* s = (const bf16*)a.src[y];
            for (int i = blockIdx.x * 256 + threadIdx.x; i < n; i += 256 * 16) d[i] = b2f(s[i]);
        } else {
            const float* s = (const float*)a.src[y];
            for (int i = blockIdx.x * 256 + threadIdx.x; i < n; i += 256 * 16) d[i] = s[i];
        }
    } else if (y < 24) {
        const int job = y - 14;
        const int z = job >> 1, half = job & 1;
        const int p = blockIdx.x * 256 + threadIdx.x;
        const void* srcs[5] = { q, k, k, v, v };
        const int clips[5] = { 0, 0, 1, 0, 1 };
        const size_t co = (size_t)clips[z] * 144 * NPIX;
        short* row = XS + (size_t)z * 655360 + (size_t)p * 160;
        for (int c0 = half * 72; c0 < half * 72 + 72; c0 += 8) {
            unsigned short h[8];
            if (isbf) {
                const bf16* s = (const bf16*)srcs[z] + co;
#pragma unroll
                for (int i = 0; i < 8; ++i) h[i] = f2bu(b2f(s[(size_t)(c0 + i) * NPIX + p]));
            } else {
                const float* s = (const float*)srcs[z] + co;
#pragma unroll
                for (int i = 0; i < 8; ++i) h[i] = f2bu(s[(size_t)(c0 + i) * NPIX + p]);
            }
            uint4 u;
            u.x = (unsigned)h[0] | ((unsigned)h[1] << 16);
            u.y = (unsigned)h[2] | ((unsigned)h[3] << 16);
            u.z = (unsigned)h[4] | ((unsigned)h[5] << 16);
            u.w = (unsigned)h[6] | ((unsigned)h[7] << 16);
            *(uint4*)(row + c0) = u;
        }
        if (half == 1) {
            uint4 zz; zz.x = zz.y = zz.z = zz.w = 0u;
            *(uint4*)(row + 144) = zz;
            *(uint4*)(row + 152) = zz;
        }
    } else if (y < 28) {
        const int sec = y - 24;
        const int p = blockIdx.x * 256 + threadIdx.x;
        short* row = X1 + (size_t)p * 448;
        if (sec < 3) {
            const void* srcs[3] = { q, vp0, vp1 };
            const int cbase = sec * 144;
            for (int c0 = 0; c0 < 144; c0 += 8) {
                unsigned short h[8];
                if (isbf) {
                    const bf16* s = (const bf16*)srcs[sec];
#pragma unroll
                    for (int i = 0; i < 8; ++i) h[i] = f2bu(b2f(s[(size_t)(c0 + i) * NPIX + p]));
                } else {
                    const float* s = (const float*)srcs[sec];
#pragma unroll
                    for (int i = 0; i < 8; ++i) h[i] = f2bu(s[(size_t)(c0 + i) * NPIX + p]);
                }
                uint4 u;
                u.x = (unsigned)h[0] | ((unsigned)h[1] << 16);
                u.y = (unsigned)h[2] | ((unsigned)h[3] << 16);
                u.z = (unsigned)h[4] | ((unsigned)h[5] << 16);
                u.w = (unsigned)h[6] | ((unsigned)h[7] << 16);
                *(uint4*)(row + cbase + c0) = u;
            }
        } else {
            unsigned short h[4];
            if (isbf) {
                const bf16* f0 = (const bf16*)fl0;
                const bf16* f1 = (const bf16*)fl1;
                h[0] = f2bu(b2f(f0[p]));
                h[1] = f2bu(b2f(f0[NPIX + p]));
                h[2] = f2bu(b2f(f1[p]));
                h[3] = f2bu(b2f(f1[NPIX + p]));
            } else {
                const float* f0 = (const float*)fl0;
                const float* f1 = (const float*)fl1;
                h[0] = f2bu(f0[p]);
                h[1] = f2bu(f0[NPIX + p]);
                h[2] = f2bu(f1[p]);
                h[3] = f2bu(f1[NPIX + p]);
            }
            uint4 u;
            u.x = (unsigned)h[0] | ((unsigned)h[1] << 16);
            u.y = (unsigned)h[2] | ((unsigned)h[3] << 16);
            u.z = 0u; u.w = 0u;
            *(uint4*)(row + 432) = u;
            uint4 zz; zz.x = zz.y = zz.z = zz.w = 0u;
            *(uint4*)(row + 440) = zz;
        }
    } else {
        PPJob J = pa.j[y - 28];
        const int tot = J.Mp * J.Kp;
        for (int e = blockIdx.x * 256 + threadIdx.x; e < tot; e += 256 * 16) {
            int m = e / J.Kp, kk = e - m * J.Kp;
            float vv = 0.f;
            if (J.kind == 0) { if (kk < J.kr) vv = rdval(J.src, m * J.sstride + kk, isbf); }
            else if (J.kind == 1) { if (kk < J.kr && m < J.mr) vv = rdval(J.src, kk * J.sstride + m, isbf); }
            else { int c = kk & 63, tap = kk >> 6; if (kk < J.kr) vv = rdval(J.src, m * J.sstride + c * 9 + tap, isbf); }
            wsS[J.dstS + e] = (short)f2bu(vv);
        }
    }
}

// ---------------- MFMA GEMM (KP compile-time -> fully unrolled K-loop) ----------------
struct GemmDesc {
    const short* A; const short* B; const float* bias;
    void* dst; void* dst2; const unsigned short* qraw;
    int Mp, Mreal, mode, gofs, ostride, obase, nwaves;
};
struct GemmDesc5 { GemmDesc d[5]; };

template <int TM, int TN, int BM, int KP>
__global__ __launch_bounds__(256) void gemm_kernel(GemmDesc5 gd)
{
    const GemmDesc d = gd.d[blockIdx.z];
    const int wid = blockIdx.x * 4 + (threadIdx.x >> 6);
    if (wid >= d.nwaves) return;
    const int lane = threadIdx.x & 63;
    const int tiles_m = d.Mp / (16 * TM);
    const int m0 = (wid % tiles_m) * (16 * TM);
    const int p0 = (wid / tiles_m) * (16 * TN);
    const int ar = lane & 15;
    const int kq = (lane >> 4) * 8;

    f32x4v acc[TM][TN];
#pragma unroll
    for (int i = 0; i < TM; ++i)
#pragma unroll
        for (int j = 0; j < TN; ++j) acc[i][j] = (f32x4v){0.f, 0.f, 0.f, 0.f};

#pragma unroll
    for (int k0 = 0; k0 < KP; k0 += 32) {
        bf16x8v a[TM], b[TN];
#pragma unroll
        for (int i = 0; i < TM; ++i)
            a[i] = *(const bf16x8v*)(d.A + (size_t)(m0 + i * 16 + ar) * KP + k0 + kq);
        if (BM == 0) {
#pragma unroll
            for (int j = 0; j < TN; ++j)
                b[j] = *(const bf16x8v*)(d.B + (size_t)(p0 + j * 16 + ar) * KP + k0 + kq);
        } else {
            const int tap = k0 >> 6;
            const int cc = (k0 & 63) + kq;
            const int dy = tap / 3 - 1, dx = tap % 3 - 1;
#pragma unroll
            for (int j = 0; j < TN; ++j) {
                const int pix = p0 + j * 16 + ar;
                const int yy = (pix >> 6) + dy, xx = (pix & 63) + dx;
                const bool ok = ((unsigned)yy < 64u) & ((unsigned)xx < 64u);
                const int np = min(max(yy, 0), 63) * 64 + min(max(xx, 0), 63);
                bf16x8v bv = *(const bf16x8v*)(d.B + (size_t)np * 64 + cc);
                if (!ok) bv = (bf16x8v)(short)0;
                b[j] = bv;
            }
        }
#pragma unroll
        for (int i = 0; i < TM; ++i)
#pragma unroll
            for (int j = 0; j < TN; ++j)
                acc[i][j] = __builtin_amdgcn_mfma_f32_16x16x32_bf16(a[i], b[j], acc[i][j], 0, 0, 0);
    }

    const int isbf = (d.mode == 5) ? detect_bf16(d.qraw) : 0;
#pragma unroll
    for (int i = 0; i < TM; ++i) {
#pragma unroll
        for (int j = 0; j < TN; ++j) {
            const int pcol = p0 + j * 16 + (lane & 15);
            const int mb = m0 + i * 16 + (lane >> 4) * 4;
            float vv[4];
#pragma unroll
            for (int r = 0; r < 4; ++r) {
                const int m = mb + r;
                vv[r] = acc[i][j][r];
                if (m < d.Mreal) vv[r] += d.bias[m];
            }
            if (d.mode == 0) {
#pragma unroll
                for (int r = 0; r < 4; ++r) vv[r] = (vv[r] >= 0.f) ? vv[r] : 0.1f * vv[r];
                uint2 u;
                u.x = (unsigned)f2bu(vv[0]) | ((unsigned)f2bu(vv[1]) << 16);
                u.y = (unsigned)f2bu(vv[2]) | ((unsigned)f2bu(vv[3]) << 16);
                *(uint2*)((unsigned short*)d.dst + (size_t)pcol * d.Mp + mb) = u;
            } else if (d.mode == 1) {
                const int g = mb / 24 + d.gofs;
                uint2 u;
                u.x = (unsigned)f2bu(vv[0]) | ((unsigned)f2bu(vv[1]) << 16);
                u.y = (unsigned)f2bu(vv[2]) | ((unsigned)f2bu(vv[3]) << 16);
                *(uint2*)((unsigned short*)d.dst +
                          ((size_t)g * NPIX + pcol) * d.ostride + (mb % 24) + d.obase) = u;
            } else if (d.mode == 3) {
                uint2 u;
                u.x = (unsigned)f2bu(vv[0]) | ((unsigned)f2bu(vv[1]) << 16);
                u.y = (unsigned)f2bu(vv[2]) | ((unsigned)f2bu(vv[3]) << 16);
                *(uint2*)((unsigned short*)d.dst + (size_t)pcol * 160 + mb) = u;
                if (mb < 144)
                    *(float4*)((float*)d.dst2 + (size_t)pcol * 144 + mb) =
                        make_float4(vv[0], vv[1], vv[2], vv[3]);
            } else if (d.mode == 4) {
#pragma unroll
                for (int r = 0; r < 4; ++r)
                    vv[r] = 0.5f * vv[r] * (1.f + erff(vv[r] * 0.70710678118654752f));
                uint2 u;
                u.x = (unsigned)f2bu(vv[0]) | ((unsigned)f2bu(vv[1]) << 16);
                u.y = (unsigned)f2bu(vv[2]) | ((unsigned)f2bu(vv[3]) << 16);
                *(uint2*)((unsigned short*)d.dst + (size_t)pcol * d.Mp + mb) = u;
            } else { // 5
#pragma unroll
                for (int r = 0; r < 4; ++r) {
                    const int m = mb + r;
                    if (m < 144) {
                        float v = vv[r] + ((float*)d.dst2)[(size_t)pcol * 144 + m];
                        if (isbf) ((unsigned short*)d.dst)[(size_t)m * NPIX + pcol] = f2bu(v);
                        else      ((float*)d.dst)[(size_t)m * NPIX + pcol] = v;
                    }
                }
            }
        }
    }
}

// ---------------- conv6: static-unrolled, writes interleaved PYX float2 -------------------
__global__ __launch_bounds__(256) void conv6_kernel(const short* __restrict__ YF,
                                                    const float* __restrict__ cw,
                                                    float* __restrict__ pyx)
{
    const int p = blockIdx.x * 256 + threadIdx.x;
    const int o0 = blockIdx.y * 16;
    const uint4* yrow = (const uint4*)(YF + (size_t)p * 64);
    const float* wb = cw + OF_WO6 + o0 * 64;

    float acc[16];
#pragma unroll
    for (int j = 0; j < 16; ++j) acc[j] = cw[OF_BO6 + o0 + j];

#pragma unroll
    for (int c = 0; c < 8; ++c) {
        uint4 u = yrow[c];
        float a0 = __uint_as_float(u.x << 16);
        float a1 = __uint_as_float(u.x & 0xFFFF0000u);
        float a2 = __uint_as_float(u.y << 16);
        float a3 = __uint_as_float(u.y & 0xFFFF0000u);
        float a4 = __uint_as_float(u.z << 16);
        float a5 = __uint_as_float(u.z & 0xFFFF0000u);
        float a6 = __uint_as_float(u.w << 16);
        float a7 = __uint_as_float(u.w & 0xFFFF0000u);
#pragma unroll
        for (int j = 0; j < 16; ++j) {
            const float* wr = wb + j * 64 + c * 8;
            acc[j] += a0 * wr[0] + a1 * wr[1] + a2 * wr[2] + a3 * wr[3]
                    + a4 * wr[4] + a5 * wr[5] + a6 * wr[6] + a7 * wr[7];
        }
    }

    const float f_y = cw[OF_FL0 + NPIX + p];
    const float f_x = cw[OF_FL0 + p];
    const float yf = (float)(p >> 6), xf = (float)(p & 63);
#pragma unroll
    for (int j = 0; j < 16; j += 2) {
        const int s = (o0 + j) >> 1;
        const int a_idx = s % 9;
        float vy = 10.f * tanhf(acc[j]);
        float vx = 10.f * tanhf(acc[j + 1]);
        float2 o;
        o.x = vy + f_y + (float)(a_idx / 3 - 1) + yf;
        o.y = vx + f_x + (float)(a_idx % 3 - 1) + xf;
        *(float2*)(pyx + 2 * ((size_t)s * NPIX + p)) = o;
    }
}

// ---------------- attention: two-pass, 32-thread teams, separate K/V, PYX ----------------
__device__ __forceinline__ float dot12(const bf16* __restrict__ row, const float* qv) {
    const uint2* s = (const uint2*)row;
    float d = 0.f;
#pragma unroll
    for (int c = 0; c < 3; ++c) {
        uint2 u = s[c];
        d += qv[c * 4 + 0] * __uint_as_float(u.x << 16);
        d += qv[c * 4 + 1] * __uint_as_float(u.x & 0xFFFF0000u);
        d += qv[c * 4 + 2] * __uint_as_float(u.y << 16);
        d += qv[c * 4 + 3] * __uint_as_float(u.y & 0xFFFF0000u);
    }
    return d;
}
__device__ __forceinline__ void acc12(float* ov, const bf16* __restrict__ row, float f) {
    const uint2* s = (const uint2*)row;
#pragma unroll
    for (int c = 0; c < 3; ++c) {
        uint2 u = s[c];
        ov[c * 4 + 0] += f * __uint_as_float(u.x << 16);
        ov[c * 4 + 1] += f * __uint_as_float(u.x & 0xFFFF0000u);
        ov[c * 4 + 2] += f * __uint_as_float(u.y << 16);
        ov[c * 4 + 3] += f * __uint_as_float(u.y & 0xFFFF0000u);
    }
}

__global__ __launch_bounds__(256) void attn_kernel(
    const bf16* __restrict__ qp, const bf16* __restrict__ kp,
    const bf16* __restrict__ vp, const float* __restrict__ pyx,
    unsigned short* __restrict__ att)
{
    const int t = blockIdx.x * 256 + threadIdx.x;
    const int ch = t & 1;
    const int clip = (t >> 1) & 1;
    const int sq = (t >> 2) & 7;       // 8-way sample split
    const int pp = t >> 5;
    const int m = pp >> 12;
    const int p = pp & 4095;

    float qv[12];
    {
        const uint2* s = (const uint2*)(qp + (size_t)(m * 4096 + p) * 24 + ch * 12);
#pragma unroll
        for (int c = 0; c < 3; ++c) {
            uint2 u = s[c];
            qv[c * 4 + 0] = __uint_as_float(u.x << 16);
            qv[c * 4 + 1] = __uint_as_float(u.x & 0xFFFF0000u);
            qv[c * 4 + 2] = __uint_as_float(u.y << 16);
            qv[c * 4 + 3] = __uint_as_float(u.y & 0xFFFF0000u);
        }
    }

    const int gidx = clip * 12 + m;
    const bf16* kb = kp + (size_t)gidx * 4096 * 24 + ch * 12;
    const bf16* vb = vp + (size_t)gidx * 4096 * 24 + ch * 12;
    const int sbase = gidx * 9;
    const int a0 = (sq == 0) ? 0 : (sq + 1);   // sq0: {0,1}; sq1..7: {2..8}
    const int na = (sq == 0) ? 2 : 1;

    float e[2], fyv[2], fxv[2];
    float mx = -1e30f;
#pragma unroll
    for (int i = 0; i < 2; ++i) {
        e[i] = -1e30f; fyv[i] = 0.f; fxv[i] = 0.f;
        if (i < na) {
            const int a = a0 + i;
            const float2 f2v = *(const float2*)(pyx + 2 * ((size_t)(sbase + a) * NPIX + p));
            const float fy = f2v.x, fx = f2v.y;
            fyv[i] = fy; fxv[i] = fx;
            const float y0 = floorf(fy), x0 = floorf(fx);
            const float wy = fy - y0, wx = fx - x0;
            const int iy = (int)y0, ix = (int)x0;
            const float w00 = (1.f - wy) * (1.f - wx), w01 = (1.f - wy) * wx;
            const float w10 = wy * (1.f - wx), w11 = wy * wx;
            float part = 0.f;
            if ((unsigned)iy < 64u) {
                const bf16* rr = kb + (size_t)(iy * 64) * 24;
                if ((unsigned)ix < 64u)       part += w00 * dot12(rr + ix * 24, qv);
                if ((unsigned)(ix + 1) < 64u) part += w01 * dot12(rr + (ix + 1) * 24, qv);
            }
            if ((unsigned)(iy + 1) < 64u) {
                const bf16* rr = kb + (size_t)((iy + 1) * 64) * 24;
                if ((unsigned)ix < 64u)       part += w10 * dot12(rr + ix * 24, qv);
                if ((unsigned)(ix + 1) < 64u) part += w11 * dot12(rr + (ix + 1) * 24, qv);
            }
            float full = part + __shfl_xor(part, 1, 64);
            e[i] = full * 0.20412414523193154f;
            mx = fmaxf(mx, e[i]);
        }
    }
    mx = fmaxf(mx, __shfl_xor(mx, 16, 64));
    mx = fmaxf(mx, __shfl_xor(mx, 8, 64));
    mx = fmaxf(mx, __shfl_xor(mx, 4, 64));
    mx = fmaxf(mx, __shfl_xor(mx, 2, 64));
    float sum = 0.f;
#pragma unroll
    for (int i = 0; i < 2; ++i) {
        if (i < na) { e[i] = __expf(e[i] - mx); sum += e[i]; }
    }
    sum += __shfl_xor(sum, 16, 64);
    sum += __shfl_xor(sum, 8, 64);
    sum += __shfl_xor(sum, 4, 64);
    sum += __shfl_xor(sum, 2, 64);
    const float inv = 1.f / sum;

    float ov[12];
#pragma unroll
    for (int j = 0; j < 12; ++j) ov[j] = 0.f;

#pragma unroll
    for (int i = 0; i < 2; ++i) {
        if (i < na) {
            const float wa = e[i] * inv;
            const float fy = fyv[i], fx = fxv[i];
            const float y0 = floorf(fy), x0 = floorf(fx);
            const float wy = fy - y0, wx = fx - x0;
            const int iy = (int)y0, ix = (int)x0;
            if ((unsigned)iy < 64u) {
                const bf16* rr = vb + (size_t)(iy * 64) * 24;
                if ((unsigned)ix < 64u)       acc12(ov, rr + ix * 24, wa * (1.f - wy) * (1.f - wx));
                if ((unsigned)(ix + 1) < 64u) acc12(ov, rr + (ix + 1) * 24, wa * (1.f - wy) * wx);
            }
            if ((unsigned)(iy + 1) < 64u) {
                const bf16* rr = vb + (size_t)((iy + 1) * 64) * 24;
                if ((unsigned)ix < 64u)       acc12(ov, rr + ix * 24, wa * wy * (1.f - wx));
                if ((unsigned)(ix + 1) < 64u) acc12(ov, rr + (ix + 1) * 24, wa * wy * wx);
            }
        }
    }
#pragma unroll
    for (int j = 0; j < 12; ++j) {
        ov[j] += __shfl_xor(ov[j], 16, 64);
        ov[j] += __shfl_xor(ov[j], 8, 64);
        ov[j] += __shfl_xor(ov[j], 4, 64);
        ov[j] += __shfl_xor(ov[j], 2, 64);
    }
    if (clip == 0 && sq == 0) {
        unsigned short* ab = att + (size_t)p * 288 + m * 24 + ch * 12;
#pragma unroll
        for (int c = 0; c < 3; ++c) {
            uint2 u;
            u.x = (unsigned)f2bu(ov[c * 4 + 0]) | ((unsigned)f2bu(ov[c * 4 + 1]) << 16);
            u.y = (unsigned)f2bu(ov[c * 4 + 2]) | ((unsigned)f2bu(ov[c * 4 + 3]) << 16);
            ((uint2*)ab)[c] = u;
        }
    }
}

// ---------------- diagnostic ----------------
__global__ void diag_kernel(float* __restrict__ out, int n, float v)
{
    int i = blockIdx.x * 256 + threadIdx.x;
    if (i < n) out[i] = (i == 0 ? v : 0.f);
}

extern "C" void kernel_launch(void* const* d_in, const int* in_sizes, int n_in,
                              void* d_out, int out_size, void* d_ws, size_t ws_size,
                              hipStream_t stream)
{
    const size_t REQUIRED = 75000000;
    if (ws_size < REQUIRED) {
        float code = 1000.0f + (float)(ws_size >> 20);
        diag_kernel<<<dim3((out_size + 255) / 256), 256, 0, stream>>>((float*)d_out, out_size, code);
        return;
    }

    char* W = (char*)d_ws;
    short* wsS = (short*)W;
    float* cw = (float*)(W + 64);

    short* conv1w = wsS + 1000000;
    short* conv3w[4] = { wsS + 1028672, wsS + 1065536, wsS + 1102400, wsS + 1139264 };
    short* wqb = wsS + 1176128, *wkb = wsS + 1222208, *wvb = wsS + 1268288;
    short* wpS = wsS + 1314368, *wm1S = wsS + 1360448, *wm2S = wsS + 1406528;

    short* XS = (short*)(W + 16777216);
    short* X1 = (short*)(W + 25165824);
    bf16*  QP = (bf16*)(W + 33554432);
    bf16*  KP = (bf16*)(W + 36700160);
    bf16*  VP = (bf16*)(W + 41943040);
    short* Y0 = (short*)(W + 50331648);
    short* Y1 = (short*)(W + 50855936);
    short* YF = (short*)(W + 51380224);
    float* PYX = (float*)(W + 54525952); // [216][4096][2] interleaved y,x fp32
    unsigned short* ATT = (unsigned short*)(W + 62914560);
    short* OPM = (short*)(W + 67108864);
    float* O32 = (float*)(W + 68419584);
    short* M1  = (short*)(W + 71303168);

    const unsigned short* qraw = (const unsigned short*)d_in[0];

    // 1. convert (only consumed tensors) + stage + prepack (fused)
    CArgs ca;
    const int srcidx[14] = {8,10,12,14,16,17,18,20,22,24,26,28,30,5};
    const int dsto[14]   = {OF_BO1,OF_BO2,OF_BO3,OF_BO4,OF_BO5,OF_WO6,OF_BO6,
                            OF_BQ,OF_BK,OF_BV,OF_BP,OF_BM1,OF_BM2,OF_FL0};
    for (int i = 0; i < 14; ++i) {
        ca.src[i] = d_in[srcidx[i]];
        ca.dstoff[i] = dsto[i];
        ca.n[i] = in_sizes[srcidx[i]];
    }
    PPArgs pp;
    pp.j[0]  = { d_in[7],  1000000, 64, 448, 436, 64,  436, 0 };
    pp.j[1]  = { d_in[9],  1028672, 64, 576, 576, 64,  576, 2 };
    pp.j[2]  = { d_in[11], 1065536, 64, 576, 576, 64,  576, 2 };
    pp.j[3]  = { d_in[13], 1102400, 64, 576, 576, 64,  576, 2 };
    pp.j[4]  = { d_in[15], 1139264, 64, 576, 576, 64,  576, 2 };
    pp.j[5]  = { d_in[19], 1176128, 288, 160, 144, 288, 288, 1 };
    pp.j[6]  = { d_in[21], 1222208, 288, 160, 144, 288, 288, 1 };
    pp.j[7]  = { d_in[23], 1268288, 288, 160, 144, 288, 288, 1 };
    pp.j[8]  = { d_in[25], 1314368, 160, 288, 288, 144, 144, 1 };
    pp.j[9]  = { d_in[27], 1360448, 288, 160, 144, 288, 288, 1 };
    pp.j[10] = { d_in[29], 1406528, 160, 288, 288, 144, 144, 1 };
    misc_kernel<<<dim3(16, 39), 256, 0, stream>>>(ca, pp, d_in[0], d_in[1], d_in[2], d_in[3],
                                                  d_in[4], d_in[5], d_in[6], cw, XS, X1, wsS);

    // 2. proj x5 (one dispatch, KP=160 unrolled), separate QP/KP/VP (stride 24)
    GemmDesc5 g3;
    const short* Xz[5] = { XS, XS + 655360, XS + 1310720, XS + 1966080, XS + 2621440 };
    const short* Az[5] = { wqb, wkb, wkb, wvb, wvb };
    const float* Bz[5] = { cw + OF_BQ, cw + OF_BK, cw + OF_BK, cw + OF_BV, cw + OF_BV };
    bf16* Dz[5] = { QP, KP, KP, VP, VP };
    const int Gz[5] = { 0, 0, 12, 0, 12 };
    for (int z = 0; z < 5; ++z)
        g3.d[z] = { Az[z], Xz[z], Bz[z], Dz[z], nullptr, qraw, 288, 288, 1, Gz[z], 24, 0, 1152 };
    gemm_kernel<2, 2, 0, 160><<<dim3(288, 1, 5), 256, 0, stream>>>(g3);

    // 3. conv1 (KP=448)
    GemmDesc5 g1;
    g1.d[0] = { conv1w, X1, cw + OF_BO1, Y0, nullptr, qraw, 64, 64, 0, 0, 0, 0, 1024 };
    gemm_kernel<1, 1, 0, 448><<<dim3(256, 1, 1), 256, 0, stream>>>(g1);

    // 4-7. conv3 chain, implicit-im2col GEMMs (KP=576)
    const float* cb[4] = { cw + OF_BO2, cw + OF_BO3, cw + OF_BO4, cw + OF_BO5 };
    short* cin[4] = { Y0, Y1, Y0, Y1 };
    short* coutp[4] = { Y1, Y0, Y1, YF };
    for (int i = 0; i < 4; ++i) {
        GemmDesc5 gc;
        gc.d[0] = { conv3w[i], cin[i], cb[i], coutp[i], nullptr, qraw, 64, 64, 0, 0, 0, 0, 1024 };
        gemm_kernel<1, 1, 1, 576><<<dim3(256, 1, 1), 256, 0, stream>>>(gc);
    }

    // 8. conv6 -> PYX (interleaved)
    conv6_kernel<<<dim3(16, 27), 256, 0, stream>>>(YF, cw, PYX);

    // 9. attention (two-pass, 32-thread teams, separate K/V, PYX)
    attn_kernel<<<dim3(6144), 256, 0, stream>>>(QP, KP, VP, PYX, ATT);

    // 10. wp GEMM (KP=288, TN=1 -> 1280 waves)
    GemmDesc5 gwp;
    gwp.d[0] = { wpS, (const short*)ATT, cw + OF_BP, OPM, O32, qraw, 160, 144, 3, 0, 0, 0, 1280 };
    gemm_kernel<2, 1, 0, 288><<<dim3(320, 1, 1), 256, 0, stream>>>(gwp);

    // 11. wm1 GEMM + gelu (KP=160, TN=1 -> 2304 waves)
    GemmDesc5 gm1;
    gm1.d[0] = { wm1S, OPM, cw + OF_BM1, M1, nullptr, qraw, 288, 288, 4, 0, 0, 0, 2304 };
    gemm_kernel<2, 1, 0, 160><<<dim3(576, 1, 1), 256, 0, stream>>>(gm1);

    // 12. wm2 GEMM + residual -> d_out (KP=288, TN=1 -> 1280 waves)
    GemmDesc5 gm2;
    gm2.d[0] = { wm2S, M1, cw + OF_BM2, d_out, O32, qraw, 160, 144, 5, 0, 0, 0, 1280 };
    gemm_kernel<2, 1, 0, 288><<<dim3(320, 1, 1), 256, 0, stream>>>(gm2);
}